// Round 1
// baseline (1373.465 us; speedup 1.0000x reference)
//
#include <hip/hip_runtime.h>
#include <math.h>

#define DCONV 16

// ---------------- CSR build ----------------

__global__ void k_zero(int* __restrict__ p, int n) {
  int i = blockIdx.x * 256 + threadIdx.x;
  if (i < n) p[i] = 0;
}

__global__ void k_deg(const int* __restrict__ ei, int E, int* __restrict__ deg) {
  int e = blockIdx.x * 256 + threadIdx.x;
  if (e >= E) return;
  atomicAdd(&deg[ei[E + e]], 1);
}

__global__ void k_block_sums(const int* __restrict__ deg, int n, int* __restrict__ part) {
  int i = blockIdx.x * 256 + threadIdx.x;
  int v = (i < n) ? deg[i] : 0;
  #pragma unroll
  for (int off = 32; off > 0; off >>= 1) v += __shfl_down(v, off, 64);
  __shared__ int ws[4];
  if ((threadIdx.x & 63) == 0) ws[threadIdx.x >> 6] = v;
  __syncthreads();
  if (threadIdx.x == 0) part[blockIdx.x] = ws[0] + ws[1] + ws[2] + ws[3];
}

// single block, 512 threads; nb <= 512
__global__ void k_scan_part(int* __restrict__ part, int nb) {
  __shared__ int s[512];
  int t = threadIdx.x;
  int v = (t < nb) ? part[t] : 0;
  s[t] = v;
  __syncthreads();
  for (int off = 1; off < 512; off <<= 1) {
    int u = (t >= off) ? s[t - off] : 0;
    __syncthreads();
    s[t] += u;
    __syncthreads();
  }
  if (t < nb) part[t] = s[t] - v;  // exclusive prefix
}

__global__ void k_rowptr(const int* __restrict__ deg, int n, const int* __restrict__ part,
                         int* __restrict__ rowptr, int* __restrict__ fill) {
  __shared__ int s[256];
  int t = threadIdx.x;
  int i = blockIdx.x * 256 + t;
  int v = (i < n) ? deg[i] : 0;
  s[t] = v;
  __syncthreads();
  for (int off = 1; off < 256; off <<= 1) {
    int u = (t >= off) ? s[t - off] : 0;
    __syncthreads();
    s[t] += u;
    __syncthreads();
  }
  int excl = s[t] - v + part[blockIdx.x];
  if (i < n) { rowptr[i] = excl; fill[i] = excl; }
  if (i == n - 1) rowptr[n] = excl + v;
}

__global__ void k_fill(const int* __restrict__ ei, int E, int* __restrict__ fill,
                       int* __restrict__ csr) {
  int e = blockIdx.x * 256 + threadIdx.x;
  if (e >= E) return;
  int s = ei[e];
  int d = ei[E + e];
  int pos = atomicAdd(&fill[d], 1);
  csr[pos] = s;
}

// ---------------- SAGE conv: mean-aggregate + dual matmul + ELU ----------------
// Group of DI lanes per node. Lane d accumulates feature d of the neighbor mean,
// then shuffle-broadcast matmul into DO=16 outputs.

template <int DI>
__global__ void k_conv(const float* __restrict__ xin, const int* __restrict__ rowptr,
                       const int* __restrict__ csr,
                       const float* __restrict__ Wl, const float* __restrict__ Wr,
                       const float* __restrict__ bias,
                       float* __restrict__ out, int n) {
  const int DO = DCONV;
  __shared__ float sWl[DI * DO], sWr[DI * DO], sb[DO];
  for (int i = threadIdx.x; i < DI * DO; i += blockDim.x) { sWl[i] = Wl[i]; sWr[i] = Wr[i]; }
  if (threadIdx.x < DO) sb[threadIdx.x] = bias[threadIdx.x];
  __syncthreads();

  int lane = threadIdx.x & (DI - 1);
  int node = (blockIdx.x * blockDim.x + threadIdx.x) / DI;
  if (node >= n) return;

  int r0 = rowptr[node], r1 = rowptr[node + 1];
  float s0 = 0.f, s1 = 0.f;
  int k = r0;
  for (; k + 1 < r1; k += 2) {     // 2-way ILP on the gather chain
    int a = csr[k], b = csr[k + 1];
    s0 += xin[a * DI + lane];
    s1 += xin[b * DI + lane];
  }
  if (k < r1) s0 += xin[csr[k] * DI + lane];
  float agg = (s0 + s1) / fmaxf((float)(r1 - r0), 1.f);
  float xv = xin[node * DI + lane];

  float h = (lane < DO) ? sb[lane] : 0.f;
  int base = (threadIdx.x & 63) & ~(DI - 1);
  #pragma unroll
  for (int i = 0; i < DI; ++i) {
    float a  = __shfl(agg, base + i, 64);
    float xr = __shfl(xv,  base + i, 64);
    if (lane < DO) h += a * sWl[i * DO + lane] + xr * sWr[i * DO + lane];
  }
  if (lane < DO) {
    out[node * DO + lane] = h > 0.f ? h : (__expf(h) - 1.f);
  }
}

// ---------------- fused 4-layer MLP ----------------
// One thread per node; h/g fully unrolled into registers; weight reads are
// wave-uniform (compiler scalarizes to s_load).

__global__ void __launch_bounds__(256) k_mlp(
    const float* __restrict__ xin,
    const float* __restrict__ W0, const float* __restrict__ B0,
    const float* __restrict__ W1, const float* __restrict__ B1,
    const float* __restrict__ W2, const float* __restrict__ B2,
    const float* __restrict__ W3, const float* __restrict__ B3,
    float* __restrict__ out, int n) {
  int node = blockIdx.x * blockDim.x + threadIdx.x;
  if (node >= n) return;
  float xi[16];
  #pragma unroll
  for (int i = 0; i < 16; ++i) xi[i] = xin[node * 16 + i];
  float h[64], g[64];
  #pragma unroll
  for (int j = 0; j < 64; ++j) {
    float a = B0[j];
    #pragma unroll
    for (int i = 0; i < 16; ++i) a += xi[i] * W0[i * 64 + j];
    h[j] = a > 0.f ? a : (__expf(a) - 1.f);
  }
  #pragma unroll
  for (int j = 0; j < 64; ++j) {
    float a = B1[j];
    #pragma unroll
    for (int i = 0; i < 64; ++i) a += h[i] * W1[i * 64 + j];
    g[j] = a > 0.f ? a : (__expf(a) - 1.f);
  }
  #pragma unroll
  for (int j = 0; j < 64; ++j) {
    float a = B2[j];
    #pragma unroll
    for (int i = 0; i < 64; ++i) a += g[i] * W2[i * 64 + j];
    h[j] = a > 0.f ? a : (__expf(a) - 1.f);
  }
  #pragma unroll
  for (int j = 0; j < 4; ++j) {
    float a = B3[j];
    #pragma unroll
    for (int i = 0; i < 64; ++i) a += h[i] * W3[i * 4 + j];
    out[node * 4 + j] = a;
  }
}

// ---------------- launch ----------------

extern "C" void kernel_launch(void* const* d_in, const int* in_sizes, int n_in,
                              void* d_out, int out_size, void* d_ws, size_t ws_size,
                              hipStream_t stream) {
  const float* x   = (const float*)d_in[0];
  const int*   ei  = (const int*)d_in[1];
  const float* Wl0 = (const float*)d_in[2];
  const float* Wr0 = (const float*)d_in[3];
  const float* bl0 = (const float*)d_in[4];
  const float* Wl1 = (const float*)d_in[5];
  const float* Wr1 = (const float*)d_in[6];
  const float* bl1 = (const float*)d_in[7];
  const float* Wl2 = (const float*)d_in[8];
  const float* Wr2 = (const float*)d_in[9];
  const float* bl2 = (const float*)d_in[10];
  const float* LW0 = (const float*)d_in[11];
  const float* LB0 = (const float*)d_in[12];
  const float* LW1 = (const float*)d_in[13];
  const float* LB1 = (const float*)d_in[14];
  const float* LW2 = (const float*)d_in[15];
  const float* LB2 = (const float*)d_in[16];
  const float* LW3 = (const float*)d_in[17];
  const float* LB3 = (const float*)d_in[18];
  float* out = (float*)d_out;

  const int N_ = in_sizes[0] / 32;   // 100000
  const int E_ = in_sizes[1] / 2;    // 3200000

  char* wsp = (char*)d_ws;
  int* deg    = (int*)wsp;  wsp += sizeof(int) * (size_t)N_;
  int* rowptr = (int*)wsp;  wsp += sizeof(int) * (size_t)(N_ + 1);
  int* fill   = (int*)wsp;  wsp += sizeof(int) * (size_t)N_;
  int* part   = (int*)wsp;  wsp += sizeof(int) * 512;
  int* csr    = (int*)wsp;  wsp += sizeof(int) * (size_t)E_;
  float* h1   = (float*)wsp; wsp += sizeof(float) * (size_t)N_ * DCONV;
  float* h2   = (float*)wsp; wsp += sizeof(float) * (size_t)N_ * DCONV;
  float* h3   = (float*)wsp; wsp += sizeof(float) * (size_t)N_ * DCONV;

  int nbN = (N_ + 255) / 256;   // 391
  int nbE = (E_ + 255) / 256;

  k_zero<<<nbN, 256, 0, stream>>>(deg, N_);
  k_deg<<<nbE, 256, 0, stream>>>(ei, E_, deg);
  k_block_sums<<<nbN, 256, 0, stream>>>(deg, N_, part);
  k_scan_part<<<1, 512, 0, stream>>>(part, nbN);
  k_rowptr<<<nbN, 256, 0, stream>>>(deg, N_, part, rowptr, fill);
  k_fill<<<nbE, 256, 0, stream>>>(ei, E_, fill, csr);

  k_conv<32><<<(N_ * 32 + 255) / 256, 256, 0, stream>>>(x,  rowptr, csr, Wl0, Wr0, bl0, h1, N_);
  k_conv<16><<<(N_ * 16 + 255) / 256, 256, 0, stream>>>(h1, rowptr, csr, Wl1, Wr1, bl1, h2, N_);
  k_conv<16><<<(N_ * 16 + 255) / 256, 256, 0, stream>>>(h2, rowptr, csr, Wl2, Wr2, bl2, h3, N_);

  k_mlp<<<nbN, 256, 0, stream>>>(h3, LW0, LB0, LW1, LB1, LW2, LB2, LW3, LB3, out, N_);
}

// Round 2
// 720.296 us; speedup vs baseline: 1.9068x; 1.9068x over previous
//
#include <hip/hip_runtime.h>
#include <math.h>

#define DCONV 16

// ---------------- CSR build ----------------

__global__ void k_zero(int* __restrict__ p, int n) {
  int i = blockIdx.x * 256 + threadIdx.x;
  if (i < n) p[i] = 0;
}

__global__ void k_deg(const int* __restrict__ ei, int E, int* __restrict__ deg) {
  int e = blockIdx.x * 256 + threadIdx.x;
  if (e >= E) return;
  atomicAdd(&deg[ei[E + e]], 1);
}

__global__ void k_block_sums(const int* __restrict__ deg, int n, int* __restrict__ part) {
  int i = blockIdx.x * 256 + threadIdx.x;
  int v = (i < n) ? deg[i] : 0;
  #pragma unroll
  for (int off = 32; off > 0; off >>= 1) v += __shfl_down(v, off, 64);
  __shared__ int ws[4];
  if ((threadIdx.x & 63) == 0) ws[threadIdx.x >> 6] = v;
  __syncthreads();
  if (threadIdx.x == 0) part[blockIdx.x] = ws[0] + ws[1] + ws[2] + ws[3];
}

// single block, 512 threads; nb <= 512
__global__ void k_scan_part(int* __restrict__ part, int nb) {
  __shared__ int s[512];
  int t = threadIdx.x;
  int v = (t < nb) ? part[t] : 0;
  s[t] = v;
  __syncthreads();
  for (int off = 1; off < 512; off <<= 1) {
    int u = (t >= off) ? s[t - off] : 0;
    __syncthreads();
    s[t] += u;
    __syncthreads();
  }
  if (t < nb) part[t] = s[t] - v;  // exclusive prefix
}

__global__ void k_rowptr(const int* __restrict__ deg, int n, const int* __restrict__ part,
                         int* __restrict__ rowptr, int* __restrict__ fill) {
  __shared__ int s[256];
  int t = threadIdx.x;
  int i = blockIdx.x * 256 + t;
  int v = (i < n) ? deg[i] : 0;
  s[t] = v;
  __syncthreads();
  for (int off = 1; off < 256; off <<= 1) {
    int u = (t >= off) ? s[t - off] : 0;
    __syncthreads();
    s[t] += u;
    __syncthreads();
  }
  int excl = s[t] - v + part[blockIdx.x];
  if (i < n) { rowptr[i] = excl; fill[i] = excl; }
  if (i == n - 1) rowptr[n] = excl + v;
}

__global__ void k_fill(const int* __restrict__ ei, int E, int* __restrict__ fill,
                       int* __restrict__ csr) {
  int e = blockIdx.x * 256 + threadIdx.x;
  if (e >= E) return;
  int s = ei[e];
  int d = ei[E + e];
  int pos = atomicAdd(&fill[d], 1);
  csr[pos] = s;
}

// ---------------- SAGE conv: mean-aggregate + dual matmul + ELU ----------------

template <int DI>
__global__ void k_conv(const float* __restrict__ xin, const int* __restrict__ rowptr,
                       const int* __restrict__ csr,
                       const float* __restrict__ Wl, const float* __restrict__ Wr,
                       const float* __restrict__ bias,
                       float* __restrict__ out, int n) {
  const int DO = DCONV;
  __shared__ float sWl[DI * DO], sWr[DI * DO], sb[DO];
  for (int i = threadIdx.x; i < DI * DO; i += blockDim.x) { sWl[i] = Wl[i]; sWr[i] = Wr[i]; }
  if (threadIdx.x < DO) sb[threadIdx.x] = bias[threadIdx.x];
  __syncthreads();

  int lane = threadIdx.x & (DI - 1);
  int node = (blockIdx.x * blockDim.x + threadIdx.x) / DI;
  if (node >= n) return;

  int r0 = rowptr[node], r1 = rowptr[node + 1];
  float s0 = 0.f, s1 = 0.f;
  int k = r0;
  for (; k + 1 < r1; k += 2) {     // 2-way ILP on the gather chain
    int a = csr[k], b = csr[k + 1];
    s0 += xin[a * DI + lane];
    s1 += xin[b * DI + lane];
  }
  if (k < r1) s0 += xin[csr[k] * DI + lane];
  float agg = (s0 + s1) / fmaxf((float)(r1 - r0), 1.f);
  float xv = xin[node * DI + lane];

  float h = (lane < DO) ? sb[lane] : 0.f;
  int base = (threadIdx.x & 63) & ~(DI - 1);
  #pragma unroll
  for (int i = 0; i < DI; ++i) {
    float a  = __shfl(agg, base + i, 64);
    float xr = __shfl(xv,  base + i, 64);
    if (lane < DO) h += a * sWl[i * DO + lane] + xr * sWr[i * DO + lane];
  }
  if (lane < DO) {
    out[node * DO + lane] = h > 0.f ? h : (__expf(h) - 1.f);
  }
}

// ---------------- fused 4-layer MLP, 16 lanes / node, 2 nodes / group ----------------
// Lane l of a 16-lane group holds elements 4l..4l+3 (a float4) of every hidden
// layer. Cross-lane reduction via shfl broadcasts; weights in LDS, read as
// conflict-free float4 (16 lanes x 16B = 256B contiguous). No runtime-indexed
// register arrays -> no scratch.

__device__ __forceinline__ float4 elu4(float4 a) {
  float4 r;
  r.x = a.x > 0.f ? a.x : (__expf(a.x) - 1.f);
  r.y = a.y > 0.f ? a.y : (__expf(a.y) - 1.f);
  r.z = a.z > 0.f ? a.z : (__expf(a.z) - 1.f);
  r.w = a.w > 0.f ? a.w : (__expf(a.w) - 1.f);
  return r;
}

// 64->64 dense layer for two nodes sharing the weight reads.
__device__ __forceinline__ void layer64x2(const float* __restrict__ sW,
                                          const float* __restrict__ sB,
                                          float4 hA, float4 hB,
                                          float4& oA, float4& oB,
                                          int l, int base) {
  float4 a = *reinterpret_cast<const float4*>(&sB[4 * l]);
  float4 b = a;
  #pragma unroll
  for (int li = 0; li < 16; ++li) {
    float a0 = __shfl(hA.x, base + li, 64);
    float a1 = __shfl(hA.y, base + li, 64);
    float a2 = __shfl(hA.z, base + li, 64);
    float a3 = __shfl(hA.w, base + li, 64);
    float b0 = __shfl(hB.x, base + li, 64);
    float b1 = __shfl(hB.y, base + li, 64);
    float b2 = __shfl(hB.z, base + li, 64);
    float b3 = __shfl(hB.w, base + li, 64);
    const float4 w0 = *reinterpret_cast<const float4*>(&sW[(4 * li + 0) * 64 + 4 * l]);
    const float4 w1 = *reinterpret_cast<const float4*>(&sW[(4 * li + 1) * 64 + 4 * l]);
    const float4 w2 = *reinterpret_cast<const float4*>(&sW[(4 * li + 2) * 64 + 4 * l]);
    const float4 w3 = *reinterpret_cast<const float4*>(&sW[(4 * li + 3) * 64 + 4 * l]);
    a.x += a0 * w0.x + a1 * w1.x + a2 * w2.x + a3 * w3.x;
    a.y += a0 * w0.y + a1 * w1.y + a2 * w2.y + a3 * w3.y;
    a.z += a0 * w0.z + a1 * w1.z + a2 * w2.z + a3 * w3.z;
    a.w += a0 * w0.w + a1 * w1.w + a2 * w2.w + a3 * w3.w;
    b.x += b0 * w0.x + b1 * w1.x + b2 * w2.x + b3 * w3.x;
    b.y += b0 * w0.y + b1 * w1.y + b2 * w2.y + b3 * w3.y;
    b.z += b0 * w0.z + b1 * w1.z + b2 * w2.z + b3 * w3.z;
    b.w += b0 * w0.w + b1 * w1.w + b2 * w2.w + b3 * w3.w;
  }
  oA = a; oB = b;
}

__global__ void __launch_bounds__(256) k_mlp(
    const float* __restrict__ xin,
    const float* __restrict__ W0, const float* __restrict__ B0,
    const float* __restrict__ W1, const float* __restrict__ B1,
    const float* __restrict__ W2, const float* __restrict__ B2,
    const float* __restrict__ W3, const float* __restrict__ B3,
    float* __restrict__ out, int n) {
  __shared__ __align__(16) float sW0[16 * 64];
  __shared__ __align__(16) float sW1[64 * 64];
  __shared__ __align__(16) float sW2[64 * 64];
  __shared__ __align__(16) float sW3[64 * 4];
  __shared__ __align__(16) float sB0[64], sB1[64], sB2[64], sB3[4];
  int t = threadIdx.x;
  for (int i = t; i < 16 * 64; i += 256) sW0[i] = W0[i];
  for (int i = t; i < 64 * 64; i += 256) sW1[i] = W1[i];
  for (int i = t; i < 64 * 64; i += 256) sW2[i] = W2[i];
  if (t < 256) sW3[t] = W3[t];
  if (t < 64) { sB0[t] = B0[t]; sB1[t] = B1[t]; sB2[t] = B2[t]; }
  if (t < 4) sB3[t] = B3[t];
  __syncthreads();

  int l = t & 15;
  int base = (t & 63) & ~15;
  int group = (blockIdx.x * blockDim.x + t) >> 4;
  int nodeA = group * 2;
  int nodeB = nodeA + 1;
  if (nodeA >= n) return;
  bool hasB = nodeB < n;

  float xA = xin[nodeA * 16 + l];
  float xB = hasB ? xin[nodeB * 16 + l] : 0.f;

  // layer0: 16 -> 64
  float4 aA = *reinterpret_cast<const float4*>(&sB0[4 * l]);
  float4 aB = aA;
  #pragma unroll
  for (int i = 0; i < 16; ++i) {
    float vA = __shfl(xA, base + i, 64);
    float vB = __shfl(xB, base + i, 64);
    const float4 w = *reinterpret_cast<const float4*>(&sW0[i * 64 + 4 * l]);
    aA.x += vA * w.x; aA.y += vA * w.y; aA.z += vA * w.z; aA.w += vA * w.w;
    aB.x += vB * w.x; aB.y += vB * w.y; aB.z += vB * w.z; aB.w += vB * w.w;
  }
  float4 hA = elu4(aA), hB = elu4(aB);

  layer64x2(sW1, sB1, hA, hB, aA, aB, l, base);
  float4 gA = elu4(aA), gB = elu4(aB);

  layer64x2(sW2, sB2, gA, gB, aA, aB, l, base);
  hA = elu4(aA); hB = elu4(aB);

  // layer3: 64 -> 4, per-lane partials then group reduce
  const float4 w0 = *reinterpret_cast<const float4*>(&sW3[(4 * l + 0) * 4]);
  const float4 w1 = *reinterpret_cast<const float4*>(&sW3[(4 * l + 1) * 4]);
  const float4 w2 = *reinterpret_cast<const float4*>(&sW3[(4 * l + 2) * 4]);
  const float4 w3 = *reinterpret_cast<const float4*>(&sW3[(4 * l + 3) * 4]);
  float4 pA, pB;
  pA.x = hA.x * w0.x + hA.y * w1.x + hA.z * w2.x + hA.w * w3.x;
  pA.y = hA.x * w0.y + hA.y * w1.y + hA.z * w2.y + hA.w * w3.y;
  pA.z = hA.x * w0.z + hA.y * w1.z + hA.z * w2.z + hA.w * w3.z;
  pA.w = hA.x * w0.w + hA.y * w1.w + hA.z * w2.w + hA.w * w3.w;
  pB.x = hB.x * w0.x + hB.y * w1.x + hB.z * w2.x + hB.w * w3.x;
  pB.y = hB.x * w0.y + hB.y * w1.y + hB.z * w2.y + hB.w * w3.y;
  pB.z = hB.x * w0.z + hB.y * w1.z + hB.z * w2.z + hB.w * w3.z;
  pB.w = hB.x * w0.w + hB.y * w1.w + hB.z * w2.w + hB.w * w3.w;
  #pragma unroll
  for (int m = 1; m < 16; m <<= 1) {
    pA.x += __shfl_xor(pA.x, m, 64); pA.y += __shfl_xor(pA.y, m, 64);
    pA.z += __shfl_xor(pA.z, m, 64); pA.w += __shfl_xor(pA.w, m, 64);
    pB.x += __shfl_xor(pB.x, m, 64); pB.y += __shfl_xor(pB.y, m, 64);
    pB.z += __shfl_xor(pB.z, m, 64); pB.w += __shfl_xor(pB.w, m, 64);
  }
  if (l == 0) {
    float4 bias = *reinterpret_cast<const float4*>(&sB3[0]);
    float4 oA = {pA.x + bias.x, pA.y + bias.y, pA.z + bias.z, pA.w + bias.w};
    *reinterpret_cast<float4*>(&out[nodeA * 4]) = oA;
    if (hasB) {
      float4 oB = {pB.x + bias.x, pB.y + bias.y, pB.z + bias.z, pB.w + bias.w};
      *reinterpret_cast<float4*>(&out[nodeB * 4]) = oB;
    }
  }
}

// ---------------- launch ----------------

extern "C" void kernel_launch(void* const* d_in, const int* in_sizes, int n_in,
                              void* d_out, int out_size, void* d_ws, size_t ws_size,
                              hipStream_t stream) {
  const float* x   = (const float*)d_in[0];
  const int*   ei  = (const int*)d_in[1];
  const float* Wl0 = (const float*)d_in[2];
  const float* Wr0 = (const float*)d_in[3];
  const float* bl0 = (const float*)d_in[4];
  const float* Wl1 = (const float*)d_in[5];
  const float* Wr1 = (const float*)d_in[6];
  const float* bl1 = (const float*)d_in[7];
  const float* Wl2 = (const float*)d_in[8];
  const float* Wr2 = (const float*)d_in[9];
  const float* bl2 = (const float*)d_in[10];
  const float* LW0 = (const float*)d_in[11];
  const float* LB0 = (const float*)d_in[12];
  const float* LW1 = (const float*)d_in[13];
  const float* LB1 = (const float*)d_in[14];
  const float* LW2 = (const float*)d_in[15];
  const float* LB2 = (const float*)d_in[16];
  const float* LW3 = (const float*)d_in[17];
  const float* LB3 = (const float*)d_in[18];
  float* out = (float*)d_out;

  const int N_ = in_sizes[0] / 32;   // 100000
  const int E_ = in_sizes[1] / 2;    // 3200000

  char* wsp = (char*)d_ws;
  int* deg    = (int*)wsp;  wsp += sizeof(int) * (size_t)N_;
  int* rowptr = (int*)wsp;  wsp += sizeof(int) * (size_t)(N_ + 1);
  int* fill   = (int*)wsp;  wsp += sizeof(int) * (size_t)N_;
  int* part   = (int*)wsp;  wsp += sizeof(int) * 512;
  int* csr    = (int*)wsp;  wsp += sizeof(int) * (size_t)E_;
  float* h1   = (float*)wsp; wsp += sizeof(float) * (size_t)N_ * DCONV;
  float* h2   = (float*)wsp; wsp += sizeof(float) * (size_t)N_ * DCONV;
  float* h3   = (float*)wsp; wsp += sizeof(float) * (size_t)N_ * DCONV;

  int nbN = (N_ + 255) / 256;   // 391
  int nbE = (E_ + 255) / 256;

  k_zero<<<nbN, 256, 0, stream>>>(deg, N_);
  k_deg<<<nbE, 256, 0, stream>>>(ei, E_, deg);
  k_block_sums<<<nbN, 256, 0, stream>>>(deg, N_, part);
  k_scan_part<<<1, 512, 0, stream>>>(part, nbN);
  k_rowptr<<<nbN, 256, 0, stream>>>(deg, N_, part, rowptr, fill);
  k_fill<<<nbE, 256, 0, stream>>>(ei, E_, fill, csr);

  k_conv<32><<<(N_ * 32 + 255) / 256, 256, 0, stream>>>(x,  rowptr, csr, Wl0, Wr0, bl0, h1, N_);
  k_conv<16><<<(N_ * 16 + 255) / 256, 256, 0, stream>>>(h1, rowptr, csr, Wl1, Wr1, bl1, h2, N_);
  k_conv<16><<<(N_ * 16 + 255) / 256, 256, 0, stream>>>(h2, rowptr, csr, Wl2, Wr2, bl2, h3, N_);

  // MLP: 16 lanes per node, 2 nodes per group -> N/2 groups
  int groups = (N_ + 1) / 2;
  int nbM = (groups * 16 + 255) / 256;
  k_mlp<<<nbM, 256, 0, stream>>>(h3, LW0, LB0, LW1, LB1, LW2, LB2, LW3, LB3, out, N_);
}

// Round 3
// 397.753 us; speedup vs baseline: 3.4531x; 1.8109x over previous
//
#include <hip/hip_runtime.h>
#include <math.h>

#define DCONV 16
#define BSH 8            // nodes per bucket = 256
#define GPART 192        // partition blocks
#define MAXNB 512

// ---------------- bucketed CSR build ----------------

// per-block bucket histogram: cnt[b * GPART + g]
__global__ void k_hist(const int* __restrict__ ei, int E, int nb_buckets, int chunk,
                       int* __restrict__ cnt) {
  __shared__ int hist[MAXNB];
  int g = blockIdx.x;
  for (int i = threadIdx.x; i < nb_buckets; i += 256) hist[i] = 0;
  __syncthreads();
  int e0 = g * chunk, e1 = min(e0 + chunk, E);
  for (int e = e0 + threadIdx.x; e < e1; e += 256)
    atomicAdd(&hist[ei[E + e] >> BSH], 1);
  __syncthreads();
  for (int i = threadIdx.x; i < nb_buckets; i += 256)
    cnt[i * GPART + g] = hist[i];
}

__global__ void k_block_sums(const int* __restrict__ in, int n, int* __restrict__ part) {
  int i = blockIdx.x * 256 + threadIdx.x;
  int v = (i < n) ? in[i] : 0;
  #pragma unroll
  for (int off = 32; off > 0; off >>= 1) v += __shfl_down(v, off, 64);
  __shared__ int ws[4];
  if ((threadIdx.x & 63) == 0) ws[threadIdx.x >> 6] = v;
  __syncthreads();
  if (threadIdx.x == 0) part[blockIdx.x] = ws[0] + ws[1] + ws[2] + ws[3];
}

// single block, 512 threads; nb <= 512
__global__ void k_scan_part(int* __restrict__ part, int nb) {
  __shared__ int s[512];
  int t = threadIdx.x;
  int v = (t < nb) ? part[t] : 0;
  s[t] = v;
  __syncthreads();
  for (int off = 1; off < 512; off <<= 1) {
    int u = (t >= off) ? s[t - off] : 0;
    __syncthreads();
    s[t] += u;
    __syncthreads();
  }
  if (t < nb) part[t] = s[t] - v;  // exclusive prefix
}

__global__ void k_excl_apply(const int* __restrict__ in, int n, const int* __restrict__ part,
                             int* __restrict__ out) {
  __shared__ int s[256];
  int t = threadIdx.x;
  int i = blockIdx.x * 256 + t;
  int v = (i < n) ? in[i] : 0;
  s[t] = v;
  __syncthreads();
  for (int off = 1; off < 256; off <<= 1) {
    int u = (t >= off) ? s[t - off] : 0;
    __syncthreads();
    s[t] += u;
    __syncthreads();
  }
  if (i < n) out[i] = s[t] - v + part[blockIdx.x];
}

// scatter edges into bucket-major temp; entry = (src<<8) | (dst & 255)
__global__ void k_scatter(const int* __restrict__ ei, int E, int nb_buckets, int chunk,
                          const int* __restrict__ off, int* __restrict__ temp) {
  __shared__ int cur[MAXNB];
  int g = blockIdx.x;
  for (int i = threadIdx.x; i < nb_buckets; i += 256) cur[i] = off[i * GPART + g];
  __syncthreads();
  int e0 = g * chunk, e1 = min(e0 + chunk, E);
  for (int e = e0 + threadIdx.x; e < e1; e += 256) {
    int s = ei[e];
    int d = ei[E + e];
    int b = d >> BSH;
    int pos = atomicAdd(&cur[b], 1);
    temp[pos] = (s << BSH) | (d & ((1 << BSH) - 1));
  }
}

// per-bucket: build rowptr via LDS scan, then fine-scatter csr (L2-resident region)
__global__ void k_fine(const int* __restrict__ temp, const int* __restrict__ off,
                       int nb_buckets, int E, int n,
                       int* __restrict__ rowptr, int* __restrict__ csr) {
  __shared__ int hist[1 << BSH];
  __shared__ int cur[1 << BSH];
  int b = blockIdx.x, t = threadIdx.x;
  int lo = off[b * GPART];
  int hi = (b == nb_buckets - 1) ? E : off[(b + 1) * GPART];
  hist[t] = 0;
  __syncthreads();
  for (int e = lo + t; e < hi; e += 256)
    atomicAdd(&hist[temp[e] & 255], 1);
  __syncthreads();
  int v = hist[t];
  cur[t] = v;
  __syncthreads();
  for (int offm = 1; offm < 256; offm <<= 1) {
    int u = (t >= offm) ? cur[t - offm] : 0;
    __syncthreads();
    cur[t] += u;
    __syncthreads();
  }
  int excl = cur[t] - v;
  int node = (b << BSH) + t;
  if (node < n) rowptr[node] = lo + excl;
  if (b == nb_buckets - 1 && t == 0) rowptr[n] = hi;
  cur[t] = lo + excl;
  __syncthreads();
  for (int e = lo + t; e < hi; e += 256) {
    int p = temp[e];
    int pos = atomicAdd(&cur[p & 255], 1);
    csr[pos] = p >> BSH;
  }
}

// ---------------- SAGE conv: mean-aggregate + dual matmul + ELU ----------------

template <int DI>
__global__ void k_conv(const float* __restrict__ xin, const int* __restrict__ rowptr,
                       const int* __restrict__ csr,
                       const float* __restrict__ Wl, const float* __restrict__ Wr,
                       const float* __restrict__ bias,
                       float* __restrict__ out, int n) {
  const int DO = DCONV;
  __shared__ float sWl[DI * DO], sWr[DI * DO], sb[DO];
  for (int i = threadIdx.x; i < DI * DO; i += blockDim.x) { sWl[i] = Wl[i]; sWr[i] = Wr[i]; }
  if (threadIdx.x < DO) sb[threadIdx.x] = bias[threadIdx.x];
  __syncthreads();

  int lane = threadIdx.x & (DI - 1);
  int node = (blockIdx.x * blockDim.x + threadIdx.x) / DI;
  if (node >= n) return;

  int r0 = rowptr[node], r1 = rowptr[node + 1];
  float s0 = 0.f, s1 = 0.f;
  int k = r0;
  for (; k + 1 < r1; k += 2) {
    int a = csr[k], b = csr[k + 1];
    s0 += xin[a * DI + lane];
    s1 += xin[b * DI + lane];
  }
  if (k < r1) s0 += xin[csr[k] * DI + lane];
  float agg = (s0 + s1) / fmaxf((float)(r1 - r0), 1.f);
  float xv = xin[node * DI + lane];

  float h = (lane < DO) ? sb[lane] : 0.f;
  int base = (threadIdx.x & 63) & ~(DI - 1);
  #pragma unroll
  for (int i = 0; i < DI; ++i) {
    float a  = __shfl(agg, base + i, 64);
    float xr = __shfl(xv,  base + i, 64);
    if (lane < DO) h += a * sWl[i * DO + lane] + xr * sWr[i * DO + lane];
  }
  if (lane < DO) {
    out[node * DO + lane] = h > 0.f ? h : (__expf(h) - 1.f);
  }
}

// ---------------- fused 4-layer MLP, 16 lanes / node, 2 nodes / group ----------------

__device__ __forceinline__ float4 elu4(float4 a) {
  float4 r;
  r.x = a.x > 0.f ? a.x : (__expf(a.x) - 1.f);
  r.y = a.y > 0.f ? a.y : (__expf(a.y) - 1.f);
  r.z = a.z > 0.f ? a.z : (__expf(a.z) - 1.f);
  r.w = a.w > 0.f ? a.w : (__expf(a.w) - 1.f);
  return r;
}

__device__ __forceinline__ void layer64x2(const float* __restrict__ sW,
                                          const float* __restrict__ sB,
                                          float4 hA, float4 hB,
                                          float4& oA, float4& oB,
                                          int l, int base) {
  float4 a = *reinterpret_cast<const float4*>(&sB[4 * l]);
  float4 b = a;
  #pragma unroll
  for (int li = 0; li < 16; ++li) {
    float a0 = __shfl(hA.x, base + li, 64);
    float a1 = __shfl(hA.y, base + li, 64);
    float a2 = __shfl(hA.z, base + li, 64);
    float a3 = __shfl(hA.w, base + li, 64);
    float b0 = __shfl(hB.x, base + li, 64);
    float b1 = __shfl(hB.y, base + li, 64);
    float b2 = __shfl(hB.z, base + li, 64);
    float b3 = __shfl(hB.w, base + li, 64);
    const float4 w0 = *reinterpret_cast<const float4*>(&sW[(4 * li + 0) * 64 + 4 * l]);
    const float4 w1 = *reinterpret_cast<const float4*>(&sW[(4 * li + 1) * 64 + 4 * l]);
    const float4 w2 = *reinterpret_cast<const float4*>(&sW[(4 * li + 2) * 64 + 4 * l]);
    const float4 w3 = *reinterpret_cast<const float4*>(&sW[(4 * li + 3) * 64 + 4 * l]);
    a.x += a0 * w0.x + a1 * w1.x + a2 * w2.x + a3 * w3.x;
    a.y += a0 * w0.y + a1 * w1.y + a2 * w2.y + a3 * w3.y;
    a.z += a0 * w0.z + a1 * w1.z + a2 * w2.z + a3 * w3.z;
    a.w += a0 * w0.w + a1 * w1.w + a2 * w2.w + a3 * w3.w;
    b.x += b0 * w0.x + b1 * w1.x + b2 * w2.x + b3 * w3.x;
    b.y += b0 * w0.y + b1 * w1.y + b2 * w2.y + b3 * w3.y;
    b.z += b0 * w0.z + b1 * w1.z + b2 * w2.z + b3 * w3.z;
    b.w += b0 * w0.w + b1 * w1.w + b2 * w2.w + b3 * w3.w;
  }
  oA = a; oB = b;
}

__global__ void __launch_bounds__(256) k_mlp(
    const float* __restrict__ xin,
    const float* __restrict__ W0, const float* __restrict__ B0,
    const float* __restrict__ W1, const float* __restrict__ B1,
    const float* __restrict__ W2, const float* __restrict__ B2,
    const float* __restrict__ W3, const float* __restrict__ B3,
    float* __restrict__ out, int n) {
  __shared__ __align__(16) float sW0[16 * 64];
  __shared__ __align__(16) float sW1[64 * 64];
  __shared__ __align__(16) float sW2[64 * 64];
  __shared__ __align__(16) float sW3[64 * 4];
  __shared__ __align__(16) float sB0[64], sB1[64], sB2[64], sB3[4];
  int t = threadIdx.x;
  for (int i = t; i < 16 * 64; i += 256) sW0[i] = W0[i];
  for (int i = t; i < 64 * 64; i += 256) sW1[i] = W1[i];
  for (int i = t; i < 64 * 64; i += 256) sW2[i] = W2[i];
  if (t < 256) sW3[t] = W3[t];
  if (t < 64) { sB0[t] = B0[t]; sB1[t] = B1[t]; sB2[t] = B2[t]; }
  if (t < 4) sB3[t] = B3[t];
  __syncthreads();

  int l = t & 15;
  int base = (t & 63) & ~15;
  int group = (blockIdx.x * blockDim.x + t) >> 4;
  int nodeA = group * 2;
  int nodeB = nodeA + 1;
  if (nodeA >= n) return;
  bool hasB = nodeB < n;

  float xA = xin[nodeA * 16 + l];
  float xB = hasB ? xin[nodeB * 16 + l] : 0.f;

  float4 aA = *reinterpret_cast<const float4*>(&sB0[4 * l]);
  float4 aB = aA;
  #pragma unroll
  for (int i = 0; i < 16; ++i) {
    float vA = __shfl(xA, base + i, 64);
    float vB = __shfl(xB, base + i, 64);
    const float4 w = *reinterpret_cast<const float4*>(&sW0[i * 64 + 4 * l]);
    aA.x += vA * w.x; aA.y += vA * w.y; aA.z += vA * w.z; aA.w += vA * w.w;
    aB.x += vB * w.x; aB.y += vB * w.y; aB.z += vB * w.z; aB.w += vB * w.w;
  }
  float4 hA = elu4(aA), hB = elu4(aB);

  layer64x2(sW1, sB1, hA, hB, aA, aB, l, base);
  float4 gA = elu4(aA), gB = elu4(aB);

  layer64x2(sW2, sB2, gA, gB, aA, aB, l, base);
  hA = elu4(aA); hB = elu4(aB);

  const float4 w0 = *reinterpret_cast<const float4*>(&sW3[(4 * l + 0) * 4]);
  const float4 w1 = *reinterpret_cast<const float4*>(&sW3[(4 * l + 1) * 4]);
  const float4 w2 = *reinterpret_cast<const float4*>(&sW3[(4 * l + 2) * 4]);
  const float4 w3 = *reinterpret_cast<const float4*>(&sW3[(4 * l + 3) * 4]);
  float4 pA, pB;
  pA.x = hA.x * w0.x + hA.y * w1.x + hA.z * w2.x + hA.w * w3.x;
  pA.y = hA.x * w0.y + hA.y * w1.y + hA.z * w2.y + hA.w * w3.y;
  pA.z = hA.x * w0.z + hA.y * w1.z + hA.z * w2.z + hA.w * w3.z;
  pA.w = hA.x * w0.w + hA.y * w1.w + hA.z * w2.w + hA.w * w3.w;
  pB.x = hB.x * w0.x + hB.y * w1.x + hB.z * w2.x + hB.w * w3.x;
  pB.y = hB.x * w0.y + hB.y * w1.y + hB.z * w2.y + hB.w * w3.y;
  pB.z = hB.x * w0.z + hB.y * w1.z + hB.z * w2.z + hB.w * w3.z;
  pB.w = hB.x * w0.w + hB.y * w1.w + hB.z * w2.w + hB.w * w3.w;
  #pragma unroll
  for (int m = 1; m < 16; m <<= 1) {
    pA.x += __shfl_xor(pA.x, m, 64); pA.y += __shfl_xor(pA.y, m, 64);
    pA.z += __shfl_xor(pA.z, m, 64); pA.w += __shfl_xor(pA.w, m, 64);
    pB.x += __shfl_xor(pB.x, m, 64); pB.y += __shfl_xor(pB.y, m, 64);
    pB.z += __shfl_xor(pB.z, m, 64); pB.w += __shfl_xor(pB.w, m, 64);
  }
  if (l == 0) {
    float4 bias = *reinterpret_cast<const float4*>(&sB3[0]);
    float4 oA = {pA.x + bias.x, pA.y + bias.y, pA.z + bias.z, pA.w + bias.w};
    *reinterpret_cast<float4*>(&out[nodeA * 4]) = oA;
    if (hasB) {
      float4 oB = {pB.x + bias.x, pB.y + bias.y, pB.z + bias.z, pB.w + bias.w};
      *reinterpret_cast<float4*>(&out[nodeB * 4]) = oB;
    }
  }
}

// ---------------- launch ----------------

extern "C" void kernel_launch(void* const* d_in, const int* in_sizes, int n_in,
                              void* d_out, int out_size, void* d_ws, size_t ws_size,
                              hipStream_t stream) {
  const float* x   = (const float*)d_in[0];
  const int*   ei  = (const int*)d_in[1];
  const float* Wl0 = (const float*)d_in[2];
  const float* Wr0 = (const float*)d_in[3];
  const float* bl0 = (const float*)d_in[4];
  const float* Wl1 = (const float*)d_in[5];
  const float* Wr1 = (const float*)d_in[6];
  const float* bl1 = (const float*)d_in[7];
  const float* Wl2 = (const float*)d_in[8];
  const float* Wr2 = (const float*)d_in[9];
  const float* bl2 = (const float*)d_in[10];
  const float* LW0 = (const float*)d_in[11];
  const float* LB0 = (const float*)d_in[12];
  const float* LW1 = (const float*)d_in[13];
  const float* LB1 = (const float*)d_in[14];
  const float* LW2 = (const float*)d_in[15];
  const float* LB2 = (const float*)d_in[16];
  const float* LW3 = (const float*)d_in[17];
  const float* LB3 = (const float*)d_in[18];
  float* out = (float*)d_out;

  const int N_ = in_sizes[0] / 32;   // 100000
  const int E_ = in_sizes[1] / 2;    // 3200000

  const int NB = (N_ + (1 << BSH) - 1) >> BSH;        // 391 buckets
  const int chunk = (E_ + GPART - 1) / GPART;
  const int n2 = NB * GPART;                           // scan length
  const int nb2 = (n2 + 255) / 256;                    // <= 512

  char* wsp = (char*)d_ws;
  int* cnt    = (int*)wsp;  wsp += sizeof(int) * (size_t)n2;
  int* off    = (int*)wsp;  wsp += sizeof(int) * (size_t)n2;
  int* part   = (int*)wsp;  wsp += sizeof(int) * 512;
  int* temp   = (int*)wsp;  wsp += sizeof(int) * (size_t)E_;
  int* csr    = (int*)wsp;  wsp += sizeof(int) * (size_t)E_;
  int* rowptr = (int*)wsp;  wsp += sizeof(int) * (size_t)(N_ + 1);
  // temp is dead after k_fine; reuse it for h1/h2 if it's big enough
  float* h1;
  float* h2;
  size_t hBytes = sizeof(float) * (size_t)N_ * DCONV;
  if (sizeof(int) * (size_t)E_ >= 2 * hBytes) {
    h1 = (float*)temp;
    h2 = (float*)((char*)temp + hBytes);
  } else {
    h1 = (float*)wsp; wsp += hBytes;
    h2 = (float*)wsp; wsp += hBytes;
  }
  float* h3 = (float*)wsp; wsp += hBytes;

  // CSR build
  k_hist<<<GPART, 256, 0, stream>>>(ei, E_, NB, chunk, cnt);
  k_block_sums<<<nb2, 256, 0, stream>>>(cnt, n2, part);
  k_scan_part<<<1, 512, 0, stream>>>(part, nb2);
  k_excl_apply<<<nb2, 256, 0, stream>>>(cnt, n2, part, off);
  k_scatter<<<GPART, 256, 0, stream>>>(ei, E_, NB, chunk, off, temp);
  k_fine<<<NB, 256, 0, stream>>>(temp, off, NB, E_, N_, rowptr, csr);

  // conv stack
  k_conv<32><<<(N_ * 32 + 255) / 256, 256, 0, stream>>>(x,  rowptr, csr, Wl0, Wr0, bl0, h1, N_);
  k_conv<16><<<(N_ * 16 + 255) / 256, 256, 0, stream>>>(h1, rowptr, csr, Wl1, Wr1, bl1, h2, N_);
  k_conv<16><<<(N_ * 16 + 255) / 256, 256, 0, stream>>>(h2, rowptr, csr, Wl2, Wr2, bl2, h3, N_);

  // MLP: 16 lanes per node, 2 nodes per group
  int groups = (N_ + 1) / 2;
  int nbM = (groups * 16 + 255) / 256;
  k_mlp<<<nbM, 256, 0, stream>>>(h3, LW0, LB0, LW1, LB1, LW2, LB2, LW3, LB3, out, N_);
}

// Round 4
// 342.346 us; speedup vs baseline: 4.0119x; 1.1618x over previous
//
#include <hip/hip_runtime.h>
#include <math.h>

#define DCONV 16
#define BSH 8            // nodes per bucket = 256
#define GPART 192        // partition blocks
#define MAXNB 512

// ---------------- bucketed CSR build ----------------

__global__ void k_hist(const int* __restrict__ ei, int E, int nb_buckets, int chunk,
                       int* __restrict__ cnt) {
  __shared__ int hist[MAXNB];
  int g = blockIdx.x;
  for (int i = threadIdx.x; i < nb_buckets; i += 256) hist[i] = 0;
  __syncthreads();
  int e0 = g * chunk, e1 = min(e0 + chunk, E);
  for (int e = e0 + threadIdx.x; e < e1; e += 256)
    atomicAdd(&hist[ei[E + e] >> BSH], 1);
  __syncthreads();
  for (int i = threadIdx.x; i < nb_buckets; i += 256)
    cnt[i * GPART + g] = hist[i];
}

__global__ void k_block_sums(const int* __restrict__ in, int n, int* __restrict__ part) {
  int i = blockIdx.x * 256 + threadIdx.x;
  int v = (i < n) ? in[i] : 0;
  #pragma unroll
  for (int off = 32; off > 0; off >>= 1) v += __shfl_down(v, off, 64);
  __shared__ int ws[4];
  if ((threadIdx.x & 63) == 0) ws[threadIdx.x >> 6] = v;
  __syncthreads();
  if (threadIdx.x == 0) part[blockIdx.x] = ws[0] + ws[1] + ws[2] + ws[3];
}

__global__ void k_scan_part(int* __restrict__ part, int nb) {
  __shared__ int s[512];
  int t = threadIdx.x;
  int v = (t < nb) ? part[t] : 0;
  s[t] = v;
  __syncthreads();
  for (int off = 1; off < 512; off <<= 1) {
    int u = (t >= off) ? s[t - off] : 0;
    __syncthreads();
    s[t] += u;
    __syncthreads();
  }
  if (t < nb) part[t] = s[t] - v;  // exclusive prefix
}

__global__ void k_excl_apply(const int* __restrict__ in, int n, const int* __restrict__ part,
                             int* __restrict__ out) {
  __shared__ int s[256];
  int t = threadIdx.x;
  int i = blockIdx.x * 256 + t;
  int v = (i < n) ? in[i] : 0;
  s[t] = v;
  __syncthreads();
  for (int off = 1; off < 256; off <<= 1) {
    int u = (t >= off) ? s[t - off] : 0;
    __syncthreads();
    s[t] += u;
    __syncthreads();
  }
  if (i < n) out[i] = s[t] - v + part[blockIdx.x];
}

__global__ void k_scatter(const int* __restrict__ ei, int E, int nb_buckets, int chunk,
                          const int* __restrict__ off, int* __restrict__ temp) {
  __shared__ int cur[MAXNB];
  int g = blockIdx.x;
  for (int i = threadIdx.x; i < nb_buckets; i += 256) cur[i] = off[i * GPART + g];
  __syncthreads();
  int e0 = g * chunk, e1 = min(e0 + chunk, E);
  for (int e = e0 + threadIdx.x; e < e1; e += 256) {
    int s = ei[e];
    int d = ei[E + e];
    int b = d >> BSH;
    int pos = atomicAdd(&cur[b], 1);
    temp[pos] = (s << BSH) | (d & ((1 << BSH) - 1));
  }
}

__global__ void k_fine(const int* __restrict__ temp, const int* __restrict__ off,
                       int nb_buckets, int E, int n,
                       int* __restrict__ rowptr, int* __restrict__ csr) {
  __shared__ int hist[1 << BSH];
  __shared__ int cur[1 << BSH];
  int b = blockIdx.x, t = threadIdx.x;
  int lo = off[b * GPART];
  int hi = (b == nb_buckets - 1) ? E : off[(b + 1) * GPART];
  hist[t] = 0;
  __syncthreads();
  for (int e = lo + t; e < hi; e += 256)
    atomicAdd(&hist[temp[e] & 255], 1);
  __syncthreads();
  int v = hist[t];
  cur[t] = v;
  __syncthreads();
  for (int offm = 1; offm < 256; offm <<= 1) {
    int u = (t >= offm) ? cur[t - offm] : 0;
    __syncthreads();
    cur[t] += u;
    __syncthreads();
  }
  int excl = cur[t] - v;
  int node = (b << BSH) + t;
  if (node < n) rowptr[node] = lo + excl;
  if (b == nb_buckets - 1 && t == 0) rowptr[n] = hi;
  cur[t] = lo + excl;
  __syncthreads();
  for (int e = lo + t; e < hi; e += 256) {
    int p = temp[e];
    int pos = atomicAdd(&cur[p & 255], 1);
    csr[pos] = p >> BSH;
  }
}

// ---------------- pre-transform kernels ----------------
// y = h @ Wl ; r = h @ Wr + b   (mean and matmul commute, so aggregate y afterward)

// 32 -> 16: 16 lanes per node; lane holds x[l] and x[16+l]
__global__ void k_xform32(const float* __restrict__ xin,
                          const float* __restrict__ Wl, const float* __restrict__ Wr,
                          const float* __restrict__ bias,
                          float* __restrict__ y, float* __restrict__ r, int n) {
  __shared__ float sWl[32 * 16], sWr[32 * 16], sb[16];
  int t = threadIdx.x;
  for (int i = t; i < 32 * 16; i += 256) { sWl[i] = Wl[i]; sWr[i] = Wr[i]; }
  if (t < 16) sb[t] = bias[t];
  __syncthreads();
  int l = t & 15;
  int base = (t & 63) & ~15;
  int node = (blockIdx.x * 256 + t) >> 4;
  if (node >= n) return;
  float x0 = xin[node * 32 + l];
  float x1 = xin[node * 32 + 16 + l];
  float ay = 0.f, ar = sb[l];
  #pragma unroll
  for (int i = 0; i < 16; ++i) {
    float v0 = __shfl(x0, base + i, 64);
    float v1 = __shfl(x1, base + i, 64);
    ay += v0 * sWl[i * 16 + l] + v1 * sWl[(16 + i) * 16 + l];
    ar += v0 * sWr[i * 16 + l] + v1 * sWr[(16 + i) * 16 + l];
  }
  y[node * 16 + l] = ay;
  r[node * 16 + l] = ar;
}

// 16 -> 16
__global__ void k_xform16(const float* __restrict__ hin,
                          const float* __restrict__ Wl, const float* __restrict__ Wr,
                          const float* __restrict__ bias,
                          float* __restrict__ y, float* __restrict__ r, int n) {
  __shared__ float sWl[16 * 16], sWr[16 * 16], sb[16];
  int t = threadIdx.x;
  for (int i = t; i < 16 * 16; i += 256) { sWl[i] = Wl[i]; sWr[i] = Wr[i]; }
  if (t < 16) sb[t] = bias[t];
  __syncthreads();
  int l = t & 15;
  int base = (t & 63) & ~15;
  int node = (blockIdx.x * 256 + t) >> 4;
  if (node >= n) return;
  float x0 = hin[node * 16 + l];
  float ay = 0.f, ar = sb[l];
  #pragma unroll
  for (int i = 0; i < 16; ++i) {
    float v0 = __shfl(x0, base + i, 64);
    ay += v0 * sWl[i * 16 + l];
    ar += v0 * sWr[i * 16 + l];
  }
  y[node * 16 + l] = ay;
  r[node * 16 + l] = ar;
}

// ---------------- aggregate: out = elu(mean_gather(y) + r) ----------------
// 4 lanes per node, float4 per lane; unroll-4 -> up to 64 lines in flight/wave.

__global__ void k_agg(const float* __restrict__ y, const float* __restrict__ r,
                      const int* __restrict__ rowptr, const int* __restrict__ csr,
                      float* __restrict__ outp, int n) {
  int t = blockIdx.x * 256 + threadIdx.x;
  int l = t & 3;
  int node = t >> 2;
  if (node >= n) return;
  int r0 = rowptr[node], r1 = rowptr[node + 1];
  float s0x = 0.f, s0y = 0.f, s0z = 0.f, s0w = 0.f;
  float s1x = 0.f, s1y = 0.f, s1z = 0.f, s1w = 0.f;
  float s2x = 0.f, s2y = 0.f, s2z = 0.f, s2w = 0.f;
  float s3x = 0.f, s3y = 0.f, s3z = 0.f, s3w = 0.f;
  int k = r0;
  for (; k + 3 < r1; k += 4) {
    int a = csr[k], b = csr[k + 1], c = csr[k + 2], d = csr[k + 3];
    float4 va = *reinterpret_cast<const float4*>(&y[a * 16 + l * 4]);
    float4 vb = *reinterpret_cast<const float4*>(&y[b * 16 + l * 4]);
    float4 vc = *reinterpret_cast<const float4*>(&y[c * 16 + l * 4]);
    float4 vd = *reinterpret_cast<const float4*>(&y[d * 16 + l * 4]);
    s0x += va.x; s0y += va.y; s0z += va.z; s0w += va.w;
    s1x += vb.x; s1y += vb.y; s1z += vb.z; s1w += vb.w;
    s2x += vc.x; s2y += vc.y; s2z += vc.z; s2w += vc.w;
    s3x += vd.x; s3y += vd.y; s3z += vd.z; s3w += vd.w;
  }
  for (; k < r1; ++k) {
    int a = csr[k];
    float4 va = *reinterpret_cast<const float4*>(&y[a * 16 + l * 4]);
    s0x += va.x; s0y += va.y; s0z += va.z; s0w += va.w;
  }
  float inv = 1.f / fmaxf((float)(r1 - r0), 1.f);
  float4 rr = *reinterpret_cast<const float4*>(&r[node * 16 + l * 4]);
  float ax = (s0x + s1x + s2x + s3x) * inv + rr.x;
  float ay = (s0y + s1y + s2y + s3y) * inv + rr.y;
  float az = (s0z + s1z + s2z + s3z) * inv + rr.z;
  float aw = (s0w + s1w + s2w + s3w) * inv + rr.w;
  float4 o;
  o.x = ax > 0.f ? ax : (__expf(ax) - 1.f);
  o.y = ay > 0.f ? ay : (__expf(ay) - 1.f);
  o.z = az > 0.f ? az : (__expf(az) - 1.f);
  o.w = aw > 0.f ? aw : (__expf(aw) - 1.f);
  *reinterpret_cast<float4*>(&outp[node * 16 + l * 4]) = o;
}

// ---------------- fused 4-layer MLP, 16 lanes / node, 2 nodes / group ----------------

__device__ __forceinline__ float4 elu4(float4 a) {
  float4 r;
  r.x = a.x > 0.f ? a.x : (__expf(a.x) - 1.f);
  r.y = a.y > 0.f ? a.y : (__expf(a.y) - 1.f);
  r.z = a.z > 0.f ? a.z : (__expf(a.z) - 1.f);
  r.w = a.w > 0.f ? a.w : (__expf(a.w) - 1.f);
  return r;
}

__device__ __forceinline__ void layer64x2(const float* __restrict__ sW,
                                          const float* __restrict__ sB,
                                          float4 hA, float4 hB,
                                          float4& oA, float4& oB,
                                          int l, int base) {
  float4 a = *reinterpret_cast<const float4*>(&sB[4 * l]);
  float4 b = a;
  #pragma unroll
  for (int li = 0; li < 16; ++li) {
    float a0 = __shfl(hA.x, base + li, 64);
    float a1 = __shfl(hA.y, base + li, 64);
    float a2 = __shfl(hA.z, base + li, 64);
    float a3 = __shfl(hA.w, base + li, 64);
    float b0 = __shfl(hB.x, base + li, 64);
    float b1 = __shfl(hB.y, base + li, 64);
    float b2 = __shfl(hB.z, base + li, 64);
    float b3 = __shfl(hB.w, base + li, 64);
    const float4 w0 = *reinterpret_cast<const float4*>(&sW[(4 * li + 0) * 64 + 4 * l]);
    const float4 w1 = *reinterpret_cast<const float4*>(&sW[(4 * li + 1) * 64 + 4 * l]);
    const float4 w2 = *reinterpret_cast<const float4*>(&sW[(4 * li + 2) * 64 + 4 * l]);
    const float4 w3 = *reinterpret_cast<const float4*>(&sW[(4 * li + 3) * 64 + 4 * l]);
    a.x += a0 * w0.x + a1 * w1.x + a2 * w2.x + a3 * w3.x;
    a.y += a0 * w0.y + a1 * w1.y + a2 * w2.y + a3 * w3.y;
    a.z += a0 * w0.z + a1 * w1.z + a2 * w2.z + a3 * w3.z;
    a.w += a0 * w0.w + a1 * w1.w + a2 * w2.w + a3 * w3.w;
    b.x += b0 * w0.x + b1 * w1.x + b2 * w2.x + b3 * w3.x;
    b.y += b0 * w0.y + b1 * w1.y + b2 * w2.y + b3 * w3.y;
    b.z += b0 * w0.z + b1 * w1.z + b2 * w2.z + b3 * w3.z;
    b.w += b0 * w0.w + b1 * w1.w + b2 * w2.w + b3 * w3.w;
  }
  oA = a; oB = b;
}

__global__ void __launch_bounds__(256) k_mlp(
    const float* __restrict__ xin,
    const float* __restrict__ W0, const float* __restrict__ B0,
    const float* __restrict__ W1, const float* __restrict__ B1,
    const float* __restrict__ W2, const float* __restrict__ B2,
    const float* __restrict__ W3, const float* __restrict__ B3,
    float* __restrict__ out, int n) {
  __shared__ __align__(16) float sW0[16 * 64];
  __shared__ __align__(16) float sW1[64 * 64];
  __shared__ __align__(16) float sW2[64 * 64];
  __shared__ __align__(16) float sW3[64 * 4];
  __shared__ __align__(16) float sB0[64], sB1[64], sB2[64], sB3[4];
  int t = threadIdx.x;
  for (int i = t; i < 16 * 64; i += 256) sW0[i] = W0[i];
  for (int i = t; i < 64 * 64; i += 256) sW1[i] = W1[i];
  for (int i = t; i < 64 * 64; i += 256) sW2[i] = W2[i];
  if (t < 256) sW3[t] = W3[t];
  if (t < 64) { sB0[t] = B0[t]; sB1[t] = B1[t]; sB2[t] = B2[t]; }
  if (t < 4) sB3[t] = B3[t];
  __syncthreads();

  int l = t & 15;
  int base = (t & 63) & ~15;
  int group = (blockIdx.x * blockDim.x + t) >> 4;
  int nodeA = group * 2;
  int nodeB = nodeA + 1;
  if (nodeA >= n) return;
  bool hasB = nodeB < n;

  float xA = xin[nodeA * 16 + l];
  float xB = hasB ? xin[nodeB * 16 + l] : 0.f;

  float4 aA = *reinterpret_cast<const float4*>(&sB0[4 * l]);
  float4 aB = aA;
  #pragma unroll
  for (int i = 0; i < 16; ++i) {
    float vA = __shfl(xA, base + i, 64);
    float vB = __shfl(xB, base + i, 64);
    const float4 w = *reinterpret_cast<const float4*>(&sW0[i * 64 + 4 * l]);
    aA.x += vA * w.x; aA.y += vA * w.y; aA.z += vA * w.z; aA.w += vA * w.w;
    aB.x += vB * w.x; aB.y += vB * w.y; aB.z += vB * w.z; aB.w += vB * w.w;
  }
  float4 hA = elu4(aA), hB = elu4(aB);

  layer64x2(sW1, sB1, hA, hB, aA, aB, l, base);
  float4 gA = elu4(aA), gB = elu4(aB);

  layer64x2(sW2, sB2, gA, gB, aA, aB, l, base);
  hA = elu4(aA); hB = elu4(aB);

  const float4 w0 = *reinterpret_cast<const float4*>(&sW3[(4 * l + 0) * 4]);
  const float4 w1 = *reinterpret_cast<const float4*>(&sW3[(4 * l + 1) * 4]);
  const float4 w2 = *reinterpret_cast<const float4*>(&sW3[(4 * l + 2) * 4]);
  const float4 w3 = *reinterpret_cast<const float4*>(&sW3[(4 * l + 3) * 4]);
  float4 pA, pB;
  pA.x = hA.x * w0.x + hA.y * w1.x + hA.z * w2.x + hA.w * w3.x;
  pA.y = hA.x * w0.y + hA.y * w1.y + hA.z * w2.y + hA.w * w3.y;
  pA.z = hA.x * w0.z + hA.y * w1.z + hA.z * w2.z + hA.w * w3.z;
  pA.w = hA.x * w0.w + hA.y * w1.w + hA.z * w2.w + hA.w * w3.w;
  pB.x = hB.x * w0.x + hB.y * w1.x + hB.z * w2.x + hB.w * w3.x;
  pB.y = hB.x * w0.y + hB.y * w1.y + hB.z * w2.y + hB.w * w3.y;
  pB.z = hB.x * w0.z + hB.y * w1.z + hB.z * w2.z + hB.w * w3.z;
  pB.w = hB.x * w0.w + hB.y * w1.w + hB.z * w2.w + hB.w * w3.w;
  #pragma unroll
  for (int m = 1; m < 16; m <<= 1) {
    pA.x += __shfl_xor(pA.x, m, 64); pA.y += __shfl_xor(pA.y, m, 64);
    pA.z += __shfl_xor(pA.z, m, 64); pA.w += __shfl_xor(pA.w, m, 64);
    pB.x += __shfl_xor(pB.x, m, 64); pB.y += __shfl_xor(pB.y, m, 64);
    pB.z += __shfl_xor(pB.z, m, 64); pB.w += __shfl_xor(pB.w, m, 64);
  }
  if (l == 0) {
    float4 bias = *reinterpret_cast<const float4*>(&sB3[0]);
    float4 oA = {pA.x + bias.x, pA.y + bias.y, pA.z + bias.z, pA.w + bias.w};
    *reinterpret_cast<float4*>(&out[nodeA * 4]) = oA;
    if (hasB) {
      float4 oB = {pB.x + bias.x, pB.y + bias.y, pB.z + bias.z, pB.w + bias.w};
      *reinterpret_cast<float4*>(&out[nodeB * 4]) = oB;
    }
  }
}

// ---------------- launch ----------------

extern "C" void kernel_launch(void* const* d_in, const int* in_sizes, int n_in,
                              void* d_out, int out_size, void* d_ws, size_t ws_size,
                              hipStream_t stream) {
  const float* x   = (const float*)d_in[0];
  const int*   ei  = (const int*)d_in[1];
  const float* Wl0 = (const float*)d_in[2];
  const float* Wr0 = (const float*)d_in[3];
  const float* bl0 = (const float*)d_in[4];
  const float* Wl1 = (const float*)d_in[5];
  const float* Wr1 = (const float*)d_in[6];
  const float* bl1 = (const float*)d_in[7];
  const float* Wl2 = (const float*)d_in[8];
  const float* Wr2 = (const float*)d_in[9];
  const float* bl2 = (const float*)d_in[10];
  const float* LW0 = (const float*)d_in[11];
  const float* LB0 = (const float*)d_in[12];
  const float* LW1 = (const float*)d_in[13];
  const float* LB1 = (const float*)d_in[14];
  const float* LW2 = (const float*)d_in[15];
  const float* LB2 = (const float*)d_in[16];
  const float* LW3 = (const float*)d_in[17];
  const float* LB3 = (const float*)d_in[18];
  float* out = (float*)d_out;

  const int N_ = in_sizes[0] / 32;   // 100000
  const int E_ = in_sizes[1] / 2;    // 3200000

  const int NB = (N_ + (1 << BSH) - 1) >> BSH;        // 391 buckets
  const int chunk = (E_ + GPART - 1) / GPART;
  const int n2 = NB * GPART;
  const int nb2 = (n2 + 255) / 256;                    // <= 512

  char* wsp = (char*)d_ws;
  int* cnt    = (int*)wsp;  wsp += sizeof(int) * (size_t)n2;
  int* off    = (int*)wsp;  wsp += sizeof(int) * (size_t)n2;
  int* part   = (int*)wsp;  wsp += sizeof(int) * 512;
  int* temp   = (int*)wsp;  wsp += sizeof(int) * (size_t)E_;   // dead after k_fine
  int* csr    = (int*)wsp;  wsp += sizeof(int) * (size_t)E_;
  size_t hBytes = sizeof(float) * (size_t)N_ * DCONV;          // 6.4 MB
  float* H2   = (float*)wsp; wsp += hBytes;
  int* rowptr = (int*)wsp;  wsp += sizeof(int) * (size_t)(N_ + 1);
  // H0/H1 reuse temp (12.8 MB >= 2 * 6.4 MB)
  float* H0 = (float*)temp;
  float* H1 = (float*)((char*)temp + hBytes);

  // CSR build
  k_hist<<<GPART, 256, 0, stream>>>(ei, E_, NB, chunk, cnt);
  k_block_sums<<<nb2, 256, 0, stream>>>(cnt, n2, part);
  k_scan_part<<<1, 512, 0, stream>>>(part, nb2);
  k_excl_apply<<<nb2, 256, 0, stream>>>(cnt, n2, part, off);
  k_scatter<<<GPART, 256, 0, stream>>>(ei, E_, NB, chunk, off, temp);
  k_fine<<<NB, 256, 0, stream>>>(temp, off, NB, E_, N_, rowptr, csr);

  int nbX = (N_ * 16 + 255) / 256;   // xform grids
  int nbA = (N_ * 4 + 255) / 256;    // agg grids

  // conv0: x -> H2(h1)   [y=H0, r=H1]
  k_xform32<<<nbX, 256, 0, stream>>>(x, Wl0, Wr0, bl0, H0, H1, N_);
  k_agg<<<nbA, 256, 0, stream>>>(H0, H1, rowptr, csr, H2, N_);
  // conv1: H2 -> H1(h2)  [y=H2 aliasing input (safe: per-thread row read-before-write), r=H0]
  k_xform16<<<nbX, 256, 0, stream>>>(H2, Wl1, Wr1, bl1, H2, H0, N_);
  k_agg<<<nbA, 256, 0, stream>>>(H2, H0, rowptr, csr, H1, N_);
  // conv2: H1 -> H2(h3)  [y=H1 aliasing input, r=H0]
  k_xform16<<<nbX, 256, 0, stream>>>(H1, Wl2, Wr2, bl2, H1, H0, N_);
  k_agg<<<nbA, 256, 0, stream>>>(H1, H0, rowptr, csr, H2, N_);

  // MLP
  int groups = (N_ + 1) / 2;
  int nbM = (groups * 16 + 255) / 256;
  k_mlp<<<nbM, 256, 0, stream>>>(H2, LW0, LB0, LW1, LB1, LW2, LB2, LW3, LB3, out, N_);
}

// Round 5
// 329.444 us; speedup vs baseline: 4.1690x; 1.0392x over previous
//
#include <hip/hip_runtime.h>
#include <math.h>

#define DCONV 16
#define BSH 8            // nodes per bucket = 256
#define GPART 192        // partition blocks
#define MAXNB 512

// ---------------- bucketed CSR build ----------------

__global__ void k_hist(const int* __restrict__ ei, int E, int nb_buckets, int chunk,
                       int* __restrict__ cnt) {
  __shared__ int hist[MAXNB];
  int g = blockIdx.x;
  for (int i = threadIdx.x; i < nb_buckets; i += 256) hist[i] = 0;
  __syncthreads();
  int e0 = g * chunk, e1 = min(e0 + chunk, E);
  for (int e = e0 + threadIdx.x; e < e1; e += 256)
    atomicAdd(&hist[ei[E + e] >> BSH], 1);
  __syncthreads();
  for (int i = threadIdx.x; i < nb_buckets; i += 256)
    cnt[i * GPART + g] = hist[i];
}

__global__ void k_block_sums(const int* __restrict__ in, int n, int* __restrict__ part) {
  int i = blockIdx.x * 256 + threadIdx.x;
  int v = (i < n) ? in[i] : 0;
  #pragma unroll
  for (int off = 32; off > 0; off >>= 1) v += __shfl_down(v, off, 64);
  __shared__ int ws[4];
  if ((threadIdx.x & 63) == 0) ws[threadIdx.x >> 6] = v;
  __syncthreads();
  if (threadIdx.x == 0) part[blockIdx.x] = ws[0] + ws[1] + ws[2] + ws[3];
}

__global__ void k_scan_part(int* __restrict__ part, int nb) {
  __shared__ int s[512];
  int t = threadIdx.x;
  int v = (t < nb) ? part[t] : 0;
  s[t] = v;
  __syncthreads();
  for (int off = 1; off < 512; off <<= 1) {
    int u = (t >= off) ? s[t - off] : 0;
    __syncthreads();
    s[t] += u;
    __syncthreads();
  }
  if (t < nb) part[t] = s[t] - v;  // exclusive prefix
}

__global__ void k_excl_apply(const int* __restrict__ in, int n, const int* __restrict__ part,
                             int* __restrict__ out) {
  __shared__ int s[256];
  int t = threadIdx.x;
  int i = blockIdx.x * 256 + t;
  int v = (i < n) ? in[i] : 0;
  s[t] = v;
  __syncthreads();
  for (int off = 1; off < 256; off <<= 1) {
    int u = (t >= off) ? s[t - off] : 0;
    __syncthreads();
    s[t] += u;
    __syncthreads();
  }
  if (i < n) out[i] = s[t] - v + part[blockIdx.x];
}

__global__ void k_scatter(const int* __restrict__ ei, int E, int nb_buckets, int chunk,
                          const int* __restrict__ off, int* __restrict__ temp) {
  __shared__ int cur[MAXNB];
  int g = blockIdx.x;
  for (int i = threadIdx.x; i < nb_buckets; i += 256) cur[i] = off[i * GPART + g];
  __syncthreads();
  int e0 = g * chunk, e1 = min(e0 + chunk, E);
  for (int e = e0 + threadIdx.x; e < e1; e += 256) {
    int s = ei[e];
    int d = ei[E + e];
    int b = d >> BSH;
    int pos = atomicAdd(&cur[b], 1);
    temp[pos] = (s << BSH) | (d & ((1 << BSH) - 1));
  }
}

__global__ void k_fine(const int* __restrict__ temp, const int* __restrict__ off,
                       int nb_buckets, int E, int n,
                       int* __restrict__ rowptr, int* __restrict__ csr) {
  __shared__ int hist[1 << BSH];
  __shared__ int cur[1 << BSH];
  int b = blockIdx.x, t = threadIdx.x;
  int lo = off[b * GPART];
  int hi = (b == nb_buckets - 1) ? E : off[(b + 1) * GPART];
  hist[t] = 0;
  __syncthreads();
  for (int e = lo + t; e < hi; e += 256)
    atomicAdd(&hist[temp[e] & 255], 1);
  __syncthreads();
  int v = hist[t];
  cur[t] = v;
  __syncthreads();
  for (int offm = 1; offm < 256; offm <<= 1) {
    int u = (t >= offm) ? cur[t - offm] : 0;
    __syncthreads();
    cur[t] += u;
    __syncthreads();
  }
  int excl = cur[t] - v;
  int node = (b << BSH) + t;
  if (node < n) rowptr[node] = lo + excl;
  if (b == nb_buckets - 1 && t == 0) rowptr[n] = hi;
  cur[t] = lo + excl;
  __syncthreads();
  for (int e = lo + t; e < hi; e += 256) {
    int p = temp[e];
    int pos = atomicAdd(&cur[p & 255], 1);
    csr[pos] = p >> BSH;
  }
}

// ---------------- pre-transform kernels ----------------
// y = h @ Wl ; r = h @ Wr + b   (mean and matmul commute, so aggregate y afterward)

__global__ void k_xform32(const float* __restrict__ xin,
                          const float* __restrict__ Wl, const float* __restrict__ Wr,
                          const float* __restrict__ bias,
                          float* __restrict__ y, float* __restrict__ r, int n) {
  __shared__ float sWl[32 * 16], sWr[32 * 16], sb[16];
  int t = threadIdx.x;
  for (int i = t; i < 32 * 16; i += 256) { sWl[i] = Wl[i]; sWr[i] = Wr[i]; }
  if (t < 16) sb[t] = bias[t];
  __syncthreads();
  int l = t & 15;
  int base = (t & 63) & ~15;
  int node = (blockIdx.x * 256 + t) >> 4;
  if (node >= n) return;
  float x0 = xin[node * 32 + l];
  float x1 = xin[node * 32 + 16 + l];
  float ay = 0.f, ar = sb[l];
  #pragma unroll
  for (int i = 0; i < 16; ++i) {
    float v0 = __shfl(x0, base + i, 64);
    float v1 = __shfl(x1, base + i, 64);
    ay += v0 * sWl[i * 16 + l] + v1 * sWl[(16 + i) * 16 + l];
    ar += v0 * sWr[i * 16 + l] + v1 * sWr[(16 + i) * 16 + l];
  }
  y[node * 16 + l] = ay;
  r[node * 16 + l] = ar;
}

__global__ void k_xform16(const float* __restrict__ hin,
                          const float* __restrict__ Wl, const float* __restrict__ Wr,
                          const float* __restrict__ bias,
                          float* __restrict__ y, float* __restrict__ r, int n) {
  __shared__ float sWl[16 * 16], sWr[16 * 16], sb[16];
  int t = threadIdx.x;
  for (int i = t; i < 16 * 16; i += 256) { sWl[i] = Wl[i]; sWr[i] = Wr[i]; }
  if (t < 16) sb[t] = bias[t];
  __syncthreads();
  int l = t & 15;
  int base = (t & 63) & ~15;
  int node = (blockIdx.x * 256 + t) >> 4;
  if (node >= n) return;
  float x0 = hin[node * 16 + l];
  float ay = 0.f, ar = sb[l];
  #pragma unroll
  for (int i = 0; i < 16; ++i) {
    float v0 = __shfl(x0, base + i, 64);
    ay += v0 * sWl[i * 16 + l];
    ar += v0 * sWr[i * 16 + l];
  }
  y[node * 16 + l] = ay;
  r[node * 16 + l] = ar;
}

// ---------------- aggregate: out = elu(mean_gather(y) + r) ----------------

__global__ void k_agg(const float* __restrict__ y, const float* __restrict__ r,
                      const int* __restrict__ rowptr, const int* __restrict__ csr,
                      float* __restrict__ outp, int n) {
  int t = blockIdx.x * 256 + threadIdx.x;
  int l = t & 3;
  int node = t >> 2;
  if (node >= n) return;
  int r0 = rowptr[node], r1 = rowptr[node + 1];
  float s0x = 0.f, s0y = 0.f, s0z = 0.f, s0w = 0.f;
  float s1x = 0.f, s1y = 0.f, s1z = 0.f, s1w = 0.f;
  float s2x = 0.f, s2y = 0.f, s2z = 0.f, s2w = 0.f;
  float s3x = 0.f, s3y = 0.f, s3z = 0.f, s3w = 0.f;
  int k = r0;
  for (; k + 3 < r1; k += 4) {
    int a = csr[k], b = csr[k + 1], c = csr[k + 2], d = csr[k + 3];
    float4 va = *reinterpret_cast<const float4*>(&y[a * 16 + l * 4]);
    float4 vb = *reinterpret_cast<const float4*>(&y[b * 16 + l * 4]);
    float4 vc = *reinterpret_cast<const float4*>(&y[c * 16 + l * 4]);
    float4 vd = *reinterpret_cast<const float4*>(&y[d * 16 + l * 4]);
    s0x += va.x; s0y += va.y; s0z += va.z; s0w += va.w;
    s1x += vb.x; s1y += vb.y; s1z += vb.z; s1w += vb.w;
    s2x += vc.x; s2y += vc.y; s2z += vc.z; s2w += vc.w;
    s3x += vd.x; s3y += vd.y; s3z += vd.z; s3w += vd.w;
  }
  for (; k < r1; ++k) {
    int a = csr[k];
    float4 va = *reinterpret_cast<const float4*>(&y[a * 16 + l * 4]);
    s0x += va.x; s0y += va.y; s0z += va.z; s0w += va.w;
  }
  float inv = 1.f / fmaxf((float)(r1 - r0), 1.f);
  float4 rr = *reinterpret_cast<const float4*>(&r[node * 16 + l * 4]);
  float ax = (s0x + s1x + s2x + s3x) * inv + rr.x;
  float ay = (s0y + s1y + s2y + s3y) * inv + rr.y;
  float az = (s0z + s1z + s2z + s3z) * inv + rr.z;
  float aw = (s0w + s1w + s2w + s3w) * inv + rr.w;
  float4 o;
  o.x = ax > 0.f ? ax : (__expf(ax) - 1.f);
  o.y = ay > 0.f ? ay : (__expf(ay) - 1.f);
  o.z = az > 0.f ? az : (__expf(az) - 1.f);
  o.w = aw > 0.f ? aw : (__expf(aw) - 1.f);
  *reinterpret_cast<float4*>(&outp[node * 16 + l * 4]) = o;
}

// ---------------- fused 4-layer MLP ----------------
// 16 lanes / node-pair group; activations in LDS rows (stride 68 floats ->
// groups of a wave land on disjoint banks); weights read directly from global
// (L1/L2-resident) as per-lane float4 -> VMEM pipe, DS pipe only carries
// broadcast-reads (same-address, conflict-free) and one write per layer.

#define HSTRIDE 68

__device__ __forceinline__ float4 elu4(float4 a) {
  float4 r;
  r.x = a.x > 0.f ? a.x : (__expf(a.x) - 1.f);
  r.y = a.y > 0.f ? a.y : (__expf(a.y) - 1.f);
  r.z = a.z > 0.f ? a.z : (__expf(a.z) - 1.f);
  r.w = a.w > 0.f ? a.w : (__expf(a.w) - 1.f);
  return r;
}

__global__ void __launch_bounds__(256) k_mlp(
    const float* __restrict__ xin,
    const float* __restrict__ W0, const float* __restrict__ B0,
    const float* __restrict__ W1, const float* __restrict__ B1,
    const float* __restrict__ W2, const float* __restrict__ B2,
    const float* __restrict__ W3, const float* __restrict__ B3,
    float* __restrict__ out, int n) {
  __shared__ __align__(16) float hrow[32 * HSTRIDE];
  int t = threadIdx.x;
  int l = t & 15;
  int gb = t >> 4;              // group in block (0..15)
  int rA = gb * 2, rB = rA + 1; // LDS rows
  int group = (blockIdx.x * 256 + t) >> 4;
  int nodeA = group * 2;
  int nodeB = nodeA + 1;
  if (nodeA >= n) return;
  bool hasB = nodeB < n;

  // stage the 16-float inputs of both nodes into LDS rows
  if (l < 4) {
    float4 v = *reinterpret_cast<const float4*>(&xin[nodeA * 16 + l * 4]);
    *reinterpret_cast<float4*>(&hrow[rA * HSTRIDE + l * 4]) = v;
  } else if (l < 8 && hasB) {
    float4 v = *reinterpret_cast<const float4*>(&xin[nodeB * 16 + (l - 4) * 4]);
    *reinterpret_cast<float4*>(&hrow[rB * HSTRIDE + (l - 4) * 4]) = v;
  }

  float4 accA, accB;

  // ---- layer0: 16 -> 64 ----
  accA = *reinterpret_cast<const float4*>(&B0[4 * l]);
  accB = accA;
  #pragma unroll
  for (int j = 0; j < 4; ++j) {
    float4 hA = *reinterpret_cast<const float4*>(&hrow[rA * HSTRIDE + j * 4]);
    float4 hB = *reinterpret_cast<const float4*>(&hrow[rB * HSTRIDE + j * 4]);
    const float4 w0 = *reinterpret_cast<const float4*>(&W0[(4 * j + 0) * 64 + 4 * l]);
    const float4 w1 = *reinterpret_cast<const float4*>(&W0[(4 * j + 1) * 64 + 4 * l]);
    const float4 w2 = *reinterpret_cast<const float4*>(&W0[(4 * j + 2) * 64 + 4 * l]);
    const float4 w3 = *reinterpret_cast<const float4*>(&W0[(4 * j + 3) * 64 + 4 * l]);
    accA.x += hA.x * w0.x + hA.y * w1.x + hA.z * w2.x + hA.w * w3.x;
    accA.y += hA.x * w0.y + hA.y * w1.y + hA.z * w2.y + hA.w * w3.y;
    accA.z += hA.x * w0.z + hA.y * w1.z + hA.z * w2.z + hA.w * w3.z;
    accA.w += hA.x * w0.w + hA.y * w1.w + hA.z * w2.w + hA.w * w3.w;
    accB.x += hB.x * w0.x + hB.y * w1.x + hB.z * w2.x + hB.w * w3.x;
    accB.y += hB.x * w0.y + hB.y * w1.y + hB.z * w2.y + hB.w * w3.y;
    accB.z += hB.x * w0.z + hB.y * w1.z + hB.z * w2.z + hB.w * w3.z;
    accB.w += hB.x * w0.w + hB.y * w1.w + hB.z * w2.w + hB.w * w3.w;
  }
  {
    float4 vA = elu4(accA), vB = elu4(accB);
    *reinterpret_cast<float4*>(&hrow[rA * HSTRIDE + l * 4]) = vA;
    *reinterpret_cast<float4*>(&hrow[rB * HSTRIDE + l * 4]) = vB;
  }

  // ---- layers 1 & 2: 64 -> 64 ----
  const float* Ws[2] = {W1, W2};
  const float* Bs[2] = {B1, B2};
  #pragma unroll
  for (int layer = 0; layer < 2; ++layer) {
    const float* __restrict__ W = Ws[layer];
    accA = *reinterpret_cast<const float4*>(&Bs[layer][4 * l]);
    accB = accA;
    #pragma unroll 4
    for (int j = 0; j < 16; ++j) {
      float4 hA = *reinterpret_cast<const float4*>(&hrow[rA * HSTRIDE + j * 4]);
      float4 hB = *reinterpret_cast<const float4*>(&hrow[rB * HSTRIDE + j * 4]);
      const float4 w0 = *reinterpret_cast<const float4*>(&W[(4 * j + 0) * 64 + 4 * l]);
      const float4 w1 = *reinterpret_cast<const float4*>(&W[(4 * j + 1) * 64 + 4 * l]);
      const float4 w2 = *reinterpret_cast<const float4*>(&W[(4 * j + 2) * 64 + 4 * l]);
      const float4 w3 = *reinterpret_cast<const float4*>(&W[(4 * j + 3) * 64 + 4 * l]);
      accA.x += hA.x * w0.x + hA.y * w1.x + hA.z * w2.x + hA.w * w3.x;
      accA.y += hA.x * w0.y + hA.y * w1.y + hA.z * w2.y + hA.w * w3.y;
      accA.z += hA.x * w0.z + hA.y * w1.z + hA.z * w2.z + hA.w * w3.z;
      accA.w += hA.x * w0.w + hA.y * w1.w + hA.z * w2.w + hA.w * w3.w;
      accB.x += hB.x * w0.x + hB.y * w1.x + hB.z * w2.x + hB.w * w3.x;
      accB.y += hB.x * w0.y + hB.y * w1.y + hB.z * w2.y + hB.w * w3.y;
      accB.z += hB.x * w0.z + hB.y * w1.z + hB.z * w2.z + hB.w * w3.z;
      accB.w += hB.x * w0.w + hB.y * w1.w + hB.z * w2.w + hB.w * w3.w;
    }
    float4 vA = elu4(accA), vB = elu4(accB);
    *reinterpret_cast<float4*>(&hrow[rA * HSTRIDE + l * 4]) = vA;
    *reinterpret_cast<float4*>(&hrow[rB * HSTRIDE + l * 4]) = vB;
  }

  // ---- layer3: 64 -> 4, per-lane partials on own h chunk, then reduce ----
  {
    float4 hA = *reinterpret_cast<const float4*>(&hrow[rA * HSTRIDE + l * 4]);
    float4 hB = *reinterpret_cast<const float4*>(&hrow[rB * HSTRIDE + l * 4]);
    const float4 w0 = *reinterpret_cast<const float4*>(&W3[(4 * l + 0) * 4]);
    const float4 w1 = *reinterpret_cast<const float4*>(&W3[(4 * l + 1) * 4]);
    const float4 w2 = *reinterpret_cast<const float4*>(&W3[(4 * l + 2) * 4]);
    const float4 w3 = *reinterpret_cast<const float4*>(&W3[(4 * l + 3) * 4]);
    float4 pA, pB;
    pA.x = hA.x * w0.x + hA.y * w1.x + hA.z * w2.x + hA.w * w3.x;
    pA.y = hA.x * w0.y + hA.y * w1.y + hA.z * w2.y + hA.w * w3.y;
    pA.z = hA.x * w0.z + hA.y * w1.z + hA.z * w2.z + hA.w * w3.z;
    pA.w = hA.x * w0.w + hA.y * w1.w + hA.z * w2.w + hA.w * w3.w;
    pB.x = hB.x * w0.x + hB.y * w1.x + hB.z * w2.x + hB.w * w3.x;
    pB.y = hB.x * w0.y + hB.y * w1.y + hB.z * w2.y + hB.w * w3.y;
    pB.z = hB.x * w0.z + hB.y * w1.z + hB.z * w2.z + hB.w * w3.z;
    pB.w = hB.x * w0.w + hB.y * w1.w + hB.z * w2.w + hB.w * w3.w;
    #pragma unroll
    for (int m = 1; m < 16; m <<= 1) {
      pA.x += __shfl_xor(pA.x, m, 64); pA.y += __shfl_xor(pA.y, m, 64);
      pA.z += __shfl_xor(pA.z, m, 64); pA.w += __shfl_xor(pA.w, m, 64);
      pB.x += __shfl_xor(pB.x, m, 64); pB.y += __shfl_xor(pB.y, m, 64);
      pB.z += __shfl_xor(pB.z, m, 64); pB.w += __shfl_xor(pB.w, m, 64);
    }
    if (l == 0) {
      float4 bias = *reinterpret_cast<const float4*>(&B3[0]);
      float4 oA = {pA.x + bias.x, pA.y + bias.y, pA.z + bias.z, pA.w + bias.w};
      *reinterpret_cast<float4*>(&out[nodeA * 4]) = oA;
      if (hasB) {
        float4 oB = {pB.x + bias.x, pB.y + bias.y, pB.z + bias.z, pB.w + bias.w};
        *reinterpret_cast<float4*>(&out[nodeB * 4]) = oB;
      }
    }
  }
}

// ---------------- launch ----------------

extern "C" void kernel_launch(void* const* d_in, const int* in_sizes, int n_in,
                              void* d_out, int out_size, void* d_ws, size_t ws_size,
                              hipStream_t stream) {
  const float* x   = (const float*)d_in[0];
  const int*   ei  = (const int*)d_in[1];
  const float* Wl0 = (const float*)d_in[2];
  const float* Wr0 = (const float*)d_in[3];
  const float* bl0 = (const float*)d_in[4];
  const float* Wl1 = (const float*)d_in[5];
  const float* Wr1 = (const float*)d_in[6];
  const float* bl1 = (const float*)d_in[7];
  const float* Wl2 = (const float*)d_in[8];
  const float* Wr2 = (const float*)d_in[9];
  const float* bl2 = (const float*)d_in[10];
  const float* LW0 = (const float*)d_in[11];
  const float* LB0 = (const float*)d_in[12];
  const float* LW1 = (const float*)d_in[13];
  const float* LB1 = (const float*)d_in[14];
  const float* LW2 = (const float*)d_in[15];
  const float* LB2 = (const float*)d_in[16];
  const float* LW3 = (const float*)d_in[17];
  const float* LB3 = (const float*)d_in[18];
  float* out = (float*)d_out;

  const int N_ = in_sizes[0] / 32;   // 100000
  const int E_ = in_sizes[1] / 2;    // 3200000

  const int NB = (N_ + (1 << BSH) - 1) >> BSH;        // 391 buckets
  const int chunk = (E_ + GPART - 1) / GPART;
  const int n2 = NB * GPART;
  const int nb2 = (n2 + 255) / 256;                    // <= 512

  char* wsp = (char*)d_ws;
  int* cnt    = (int*)wsp;  wsp += sizeof(int) * (size_t)n2;
  int* off    = (int*)wsp;  wsp += sizeof(int) * (size_t)n2;
  int* part   = (int*)wsp;  wsp += sizeof(int) * 512;
  int* temp   = (int*)wsp;  wsp += sizeof(int) * (size_t)E_;   // dead after k_fine
  int* csr    = (int*)wsp;  wsp += sizeof(int) * (size_t)E_;
  size_t hBytes = sizeof(float) * (size_t)N_ * DCONV;          // 6.4 MB
  float* H2   = (float*)wsp; wsp += hBytes;
  int* rowptr = (int*)wsp;  wsp += sizeof(int) * (size_t)(N_ + 1);
  float* H0 = (float*)temp;
  float* H1 = (float*)((char*)temp + hBytes);

  // CSR build
  k_hist<<<GPART, 256, 0, stream>>>(ei, E_, NB, chunk, cnt);
  k_block_sums<<<nb2, 256, 0, stream>>>(cnt, n2, part);
  k_scan_part<<<1, 512, 0, stream>>>(part, nb2);
  k_excl_apply<<<nb2, 256, 0, stream>>>(cnt, n2, part, off);
  k_scatter<<<GPART, 256, 0, stream>>>(ei, E_, NB, chunk, off, temp);
  k_fine<<<NB, 256, 0, stream>>>(temp, off, NB, E_, N_, rowptr, csr);

  int nbX = (N_ * 16 + 255) / 256;   // xform grids
  int nbA = (N_ * 4 + 255) / 256;    // agg grids

  // conv0: x -> H2(h1)   [y=H0, r=H1]
  k_xform32<<<nbX, 256, 0, stream>>>(x, Wl0, Wr0, bl0, H0, H1, N_);
  k_agg<<<nbA, 256, 0, stream>>>(H0, H1, rowptr, csr, H2, N_);
  // conv1: H2 -> H1(h2)
  k_xform16<<<nbX, 256, 0, stream>>>(H2, Wl1, Wr1, bl1, H2, H0, N_);
  k_agg<<<nbA, 256, 0, stream>>>(H2, H0, rowptr, csr, H1, N_);
  // conv2: H1 -> H2(h3)
  k_xform16<<<nbX, 256, 0, stream>>>(H1, Wl2, Wr2, bl2, H1, H0, N_);
  k_agg<<<nbA, 256, 0, stream>>>(H1, H0, rowptr, csr, H2, N_);

  // MLP
  int groups = (N_ + 1) / 2;
  int nbM = (groups * 16 + 255) / 256;
  k_mlp<<<nbM, 256, 0, stream>>>(H2, LW0, LB0, LW1, LB1, LW2, LB2, LW3, LB3, out, N_);
}

// Round 6
// 306.252 us; speedup vs baseline: 4.4848x; 1.0757x over previous
//
#include <hip/hip_runtime.h>
#include <math.h>

#define DCONV 16
#define BSH 8            // nodes per bucket = 256
#define GPART 192        // partition blocks
#define MAXNB 512

// ---------------- bucketed CSR build ----------------

__global__ void k_hist(const int* __restrict__ ei, int E, int nb_buckets, int chunk,
                       int* __restrict__ cnt) {
  __shared__ int hist[MAXNB];
  int g = blockIdx.x;
  for (int i = threadIdx.x; i < nb_buckets; i += 256) hist[i] = 0;
  __syncthreads();
  int e0 = g * chunk, e1 = min(e0 + chunk, E);
  for (int e = e0 + threadIdx.x; e < e1; e += 256)
    atomicAdd(&hist[ei[E + e] >> BSH], 1);
  __syncthreads();
  for (int i = threadIdx.x; i < nb_buckets; i += 256)
    cnt[i * GPART + g] = hist[i];
}

__global__ void k_block_sums(const int* __restrict__ in, int n, int* __restrict__ part) {
  int i = blockIdx.x * 256 + threadIdx.x;
  int v = (i < n) ? in[i] : 0;
  #pragma unroll
  for (int off = 32; off > 0; off >>= 1) v += __shfl_down(v, off, 64);
  __shared__ int ws[4];
  if ((threadIdx.x & 63) == 0) ws[threadIdx.x >> 6] = v;
  __syncthreads();
  if (threadIdx.x == 0) part[blockIdx.x] = ws[0] + ws[1] + ws[2] + ws[3];
}

__global__ void k_scan_part(int* __restrict__ part, int nb) {
  __shared__ int s[512];
  int t = threadIdx.x;
  int v = (t < nb) ? part[t] : 0;
  s[t] = v;
  __syncthreads();
  for (int off = 1; off < 512; off <<= 1) {
    int u = (t >= off) ? s[t - off] : 0;
    __syncthreads();
    s[t] += u;
    __syncthreads();
  }
  if (t < nb) part[t] = s[t] - v;  // exclusive prefix
}

__global__ void k_excl_apply(const int* __restrict__ in, int n, const int* __restrict__ part,
                             int* __restrict__ out) {
  __shared__ int s[256];
  int t = threadIdx.x;
  int i = blockIdx.x * 256 + t;
  int v = (i < n) ? in[i] : 0;
  s[t] = v;
  __syncthreads();
  for (int off = 1; off < 256; off <<= 1) {
    int u = (t >= off) ? s[t - off] : 0;
    __syncthreads();
    s[t] += u;
    __syncthreads();
  }
  if (i < n) out[i] = s[t] - v + part[blockIdx.x];
}

__global__ void k_scatter(const int* __restrict__ ei, int E, int nb_buckets, int chunk,
                          const int* __restrict__ off, int* __restrict__ temp) {
  __shared__ int cur[MAXNB];
  int g = blockIdx.x;
  for (int i = threadIdx.x; i < nb_buckets; i += 256) cur[i] = off[i * GPART + g];
  __syncthreads();
  int e0 = g * chunk, e1 = min(e0 + chunk, E);
  for (int e = e0 + threadIdx.x; e < e1; e += 256) {
    int s = ei[e];
    int d = ei[E + e];
    int b = d >> BSH;
    int pos = atomicAdd(&cur[b], 1);
    temp[pos] = (s << BSH) | (d & ((1 << BSH) - 1));
  }
}

__global__ void k_fine(const int* __restrict__ temp, const int* __restrict__ off,
                       int nb_buckets, int E, int n,
                       int* __restrict__ rowptr, int* __restrict__ csr) {
  __shared__ int hist[1 << BSH];
  __shared__ int cur[1 << BSH];
  int b = blockIdx.x, t = threadIdx.x;
  int lo = off[b * GPART];
  int hi = (b == nb_buckets - 1) ? E : off[(b + 1) * GPART];
  hist[t] = 0;
  __syncthreads();
  for (int e = lo + t; e < hi; e += 256)
    atomicAdd(&hist[temp[e] & 255], 1);
  __syncthreads();
  int v = hist[t];
  cur[t] = v;
  __syncthreads();
  for (int offm = 1; offm < 256; offm <<= 1) {
    int u = (t >= offm) ? cur[t - offm] : 0;
    __syncthreads();
    cur[t] += u;
    __syncthreads();
  }
  int excl = cur[t] - v;
  int node = (b << BSH) + t;
  if (node < n) rowptr[node] = lo + excl;
  if (b == nb_buckets - 1 && t == 0) rowptr[n] = hi;
  cur[t] = lo + excl;
  __syncthreads();
  for (int e = lo + t; e < hi; e += 256) {
    int p = temp[e];
    int pos = atomicAdd(&cur[p & 255], 1);
    csr[pos] = p >> BSH;
  }
}

// ---------------- pre-transform kernels ----------------
// y = h @ Wl ; r = h @ Wr + b   (mean and matmul commute, so aggregate y afterward)

__global__ void k_xform32(const float* __restrict__ xin,
                          const float* __restrict__ Wl, const float* __restrict__ Wr,
                          const float* __restrict__ bias,
                          float* __restrict__ y, float* __restrict__ r, int n) {
  __shared__ float sWl[32 * 16], sWr[32 * 16], sb[16];
  int t = threadIdx.x;
  for (int i = t; i < 32 * 16; i += 256) { sWl[i] = Wl[i]; sWr[i] = Wr[i]; }
  if (t < 16) sb[t] = bias[t];
  __syncthreads();
  int l = t & 15;
  int base = (t & 63) & ~15;
  int node = (blockIdx.x * 256 + t) >> 4;
  if (node >= n) return;
  float x0 = xin[node * 32 + l];
  float x1 = xin[node * 32 + 16 + l];
  float ay = 0.f, ar = sb[l];
  #pragma unroll
  for (int i = 0; i < 16; ++i) {
    float v0 = __shfl(x0, base + i, 64);
    float v1 = __shfl(x1, base + i, 64);
    ay += v0 * sWl[i * 16 + l] + v1 * sWl[(16 + i) * 16 + l];
    ar += v0 * sWr[i * 16 + l] + v1 * sWr[(16 + i) * 16 + l];
  }
  y[node * 16 + l] = ay;
  r[node * 16 + l] = ar;
}

__global__ void k_xform16(const float* __restrict__ hin,
                          const float* __restrict__ Wl, const float* __restrict__ Wr,
                          const float* __restrict__ bias,
                          float* __restrict__ y, float* __restrict__ r, int n) {
  __shared__ float sWl[16 * 16], sWr[16 * 16], sb[16];
  int t = threadIdx.x;
  for (int i = t; i < 16 * 16; i += 256) { sWl[i] = Wl[i]; sWr[i] = Wr[i]; }
  if (t < 16) sb[t] = bias[t];
  __syncthreads();
  int l = t & 15;
  int base = (t & 63) & ~15;
  int node = (blockIdx.x * 256 + t) >> 4;
  if (node >= n) return;
  float x0 = hin[node * 16 + l];
  float ay = 0.f, ar = sb[l];
  #pragma unroll
  for (int i = 0; i < 16; ++i) {
    float v0 = __shfl(x0, base + i, 64);
    ay += v0 * sWl[i * 16 + l];
    ar += v0 * sWr[i * 16 + l];
  }
  y[node * 16 + l] = ay;
  r[node * 16 + l] = ar;
}

// ---------------- aggregate: out = elu(mean_gather(y) + r) ----------------

__global__ void k_agg(const float* __restrict__ y, const float* __restrict__ r,
                      const int* __restrict__ rowptr, const int* __restrict__ csr,
                      float* __restrict__ outp, int n) {
  int t = blockIdx.x * 256 + threadIdx.x;
  int l = t & 3;
  int node = t >> 2;
  if (node >= n) return;
  int r0 = rowptr[node], r1 = rowptr[node + 1];
  float s0x = 0.f, s0y = 0.f, s0z = 0.f, s0w = 0.f;
  float s1x = 0.f, s1y = 0.f, s1z = 0.f, s1w = 0.f;
  float s2x = 0.f, s2y = 0.f, s2z = 0.f, s2w = 0.f;
  float s3x = 0.f, s3y = 0.f, s3z = 0.f, s3w = 0.f;
  int k = r0;
  for (; k + 3 < r1; k += 4) {
    int a = csr[k], b = csr[k + 1], c = csr[k + 2], d = csr[k + 3];
    float4 va = *reinterpret_cast<const float4*>(&y[a * 16 + l * 4]);
    float4 vb = *reinterpret_cast<const float4*>(&y[b * 16 + l * 4]);
    float4 vc = *reinterpret_cast<const float4*>(&y[c * 16 + l * 4]);
    float4 vd = *reinterpret_cast<const float4*>(&y[d * 16 + l * 4]);
    s0x += va.x; s0y += va.y; s0z += va.z; s0w += va.w;
    s1x += vb.x; s1y += vb.y; s1z += vb.z; s1w += vb.w;
    s2x += vc.x; s2y += vc.y; s2z += vc.z; s2w += vc.w;
    s3x += vd.x; s3y += vd.y; s3z += vd.z; s3w += vd.w;
  }
  for (; k < r1; ++k) {
    int a = csr[k];
    float4 va = *reinterpret_cast<const float4*>(&y[a * 16 + l * 4]);
    s0x += va.x; s0y += va.y; s0z += va.z; s0w += va.w;
  }
  float inv = 1.f / fmaxf((float)(r1 - r0), 1.f);
  float4 rr = *reinterpret_cast<const float4*>(&r[node * 16 + l * 4]);
  float ax = (s0x + s1x + s2x + s3x) * inv + rr.x;
  float ay = (s0y + s1y + s2y + s3y) * inv + rr.y;
  float az = (s0z + s1z + s2z + s3z) * inv + rr.z;
  float aw = (s0w + s1w + s2w + s3w) * inv + rr.w;
  float4 o;
  o.x = ax > 0.f ? ax : (__expf(ax) - 1.f);
  o.y = ay > 0.f ? ay : (__expf(ay) - 1.f);
  o.z = az > 0.f ? az : (__expf(az) - 1.f);
  o.w = aw > 0.f ? aw : (__expf(aw) - 1.f);
  *reinterpret_cast<float4*>(&outp[node * 16 + l * 4]) = o;
}

// ---------------- fused 4-layer MLP ----------------
// 16 lanes per group, 4 nodes per group. Activations in LDS rows (stride 68
// floats, rows private per group, intra-wave so no barriers); weights read
// from global (L1-resident) as per-lane float4, amortized over 4 nodes.
// Layer 3 uses an LDS-transposed W3 so each lane computes one output scalar
// (no cross-lane reduction; stores are 64 consecutive floats per wave).

#define HSTRIDE 68

__device__ __forceinline__ float4 elu4(float4 a) {
  float4 r;
  r.x = a.x > 0.f ? a.x : (__expf(a.x) - 1.f);
  r.y = a.y > 0.f ? a.y : (__expf(a.y) - 1.f);
  r.z = a.z > 0.f ? a.z : (__expf(a.z) - 1.f);
  r.w = a.w > 0.f ? a.w : (__expf(a.w) - 1.f);
  return r;
}

__device__ __forceinline__ void fma16(float4& a, const float4 h,
                                      const float4 w0, const float4 w1,
                                      const float4 w2, const float4 w3) {
  a.x += h.x * w0.x + h.y * w1.x + h.z * w2.x + h.w * w3.x;
  a.y += h.x * w0.y + h.y * w1.y + h.z * w2.y + h.w * w3.y;
  a.z += h.x * w0.z + h.y * w1.z + h.z * w2.z + h.w * w3.z;
  a.w += h.x * w0.w + h.y * w1.w + h.z * w2.w + h.w * w3.w;
}

__global__ void __launch_bounds__(256) k_mlp(
    const float* __restrict__ xin,
    const float* __restrict__ W0, const float* __restrict__ B0,
    const float* __restrict__ W1, const float* __restrict__ B1,
    const float* __restrict__ W2, const float* __restrict__ B2,
    const float* __restrict__ W3, const float* __restrict__ B3,
    float* __restrict__ out, int n) {
  __shared__ __align__(16) float hrow[64 * HSTRIDE];  // 16 groups * 4 rows
  __shared__ __align__(16) float sW3T[4 * 64];        // W3 transposed: [c][i]
  int t = threadIdx.x;
  int l = t & 15;
  int gb = t >> 4;
  int group = blockIdx.x * 16 + gb;
  int nodeBase = group * 4;
  bool active = nodeBase < n;
  int row0 = gb * 4;

  // transpose W3 into LDS (once per block)
  sW3T[(t & 3) * 64 + (t >> 2)] = W3[t];

  // stage inputs: lane l covers 4 floats of the group's 4*16 input block
  if (active) {
    int nd = l >> 2;
    float4 v = make_float4(0.f, 0.f, 0.f, 0.f);
    if (nodeBase + nd < n)
      v = *reinterpret_cast<const float4*>(&xin[nodeBase * 16 + l * 4]);
    *reinterpret_cast<float4*>(&hrow[(row0 + nd) * HSTRIDE + (l & 3) * 4]) = v;
  }
  __syncthreads();

  if (active) {
    float4 acc0, acc1, acc2, acc3;

    // ---- layer0: 16 -> 64 ----
    acc0 = *reinterpret_cast<const float4*>(&B0[4 * l]);
    acc1 = acc0; acc2 = acc0; acc3 = acc0;
    #pragma unroll
    for (int j = 0; j < 4; ++j) {
      float4 h0 = *reinterpret_cast<const float4*>(&hrow[(row0 + 0) * HSTRIDE + j * 4]);
      float4 h1 = *reinterpret_cast<const float4*>(&hrow[(row0 + 1) * HSTRIDE + j * 4]);
      float4 h2 = *reinterpret_cast<const float4*>(&hrow[(row0 + 2) * HSTRIDE + j * 4]);
      float4 h3 = *reinterpret_cast<const float4*>(&hrow[(row0 + 3) * HSTRIDE + j * 4]);
      float4 w0 = *reinterpret_cast<const float4*>(&W0[(4 * j + 0) * 64 + 4 * l]);
      float4 w1 = *reinterpret_cast<const float4*>(&W0[(4 * j + 1) * 64 + 4 * l]);
      float4 w2 = *reinterpret_cast<const float4*>(&W0[(4 * j + 2) * 64 + 4 * l]);
      float4 w3 = *reinterpret_cast<const float4*>(&W0[(4 * j + 3) * 64 + 4 * l]);
      fma16(acc0, h0, w0, w1, w2, w3);
      fma16(acc1, h1, w0, w1, w2, w3);
      fma16(acc2, h2, w0, w1, w2, w3);
      fma16(acc3, h3, w0, w1, w2, w3);
    }
    *reinterpret_cast<float4*>(&hrow[(row0 + 0) * HSTRIDE + l * 4]) = elu4(acc0);
    *reinterpret_cast<float4*>(&hrow[(row0 + 1) * HSTRIDE + l * 4]) = elu4(acc1);
    *reinterpret_cast<float4*>(&hrow[(row0 + 2) * HSTRIDE + l * 4]) = elu4(acc2);
    *reinterpret_cast<float4*>(&hrow[(row0 + 3) * HSTRIDE + l * 4]) = elu4(acc3);

    // ---- layers 1 & 2: 64 -> 64 ----
    const float* Ws[2] = {W1, W2};
    const float* Bs[2] = {B1, B2};
    #pragma unroll
    for (int layer = 0; layer < 2; ++layer) {
      const float* __restrict__ W = Ws[layer];
      acc0 = *reinterpret_cast<const float4*>(&Bs[layer][4 * l]);
      acc1 = acc0; acc2 = acc0; acc3 = acc0;
      #pragma unroll 4
      for (int j = 0; j < 16; ++j) {
        float4 h0 = *reinterpret_cast<const float4*>(&hrow[(row0 + 0) * HSTRIDE + j * 4]);
        float4 h1 = *reinterpret_cast<const float4*>(&hrow[(row0 + 1) * HSTRIDE + j * 4]);
        float4 h2 = *reinterpret_cast<const float4*>(&hrow[(row0 + 2) * HSTRIDE + j * 4]);
        float4 h3 = *reinterpret_cast<const float4*>(&hrow[(row0 + 3) * HSTRIDE + j * 4]);
        float4 w0 = *reinterpret_cast<const float4*>(&W[(4 * j + 0) * 64 + 4 * l]);
        float4 w1 = *reinterpret_cast<const float4*>(&W[(4 * j + 1) * 64 + 4 * l]);
        float4 w2 = *reinterpret_cast<const float4*>(&W[(4 * j + 2) * 64 + 4 * l]);
        float4 w3 = *reinterpret_cast<const float4*>(&W[(4 * j + 3) * 64 + 4 * l]);
        fma16(acc0, h0, w0, w1, w2, w3);
        fma16(acc1, h1, w0, w1, w2, w3);
        fma16(acc2, h2, w0, w1, w2, w3);
        fma16(acc3, h3, w0, w1, w2, w3);
      }
      *reinterpret_cast<float4*>(&hrow[(row0 + 0) * HSTRIDE + l * 4]) = elu4(acc0);
      *reinterpret_cast<float4*>(&hrow[(row0 + 1) * HSTRIDE + l * 4]) = elu4(acc1);
      *reinterpret_cast<float4*>(&hrow[(row0 + 2) * HSTRIDE + l * 4]) = elu4(acc2);
      *reinterpret_cast<float4*>(&hrow[(row0 + 3) * HSTRIDE + l * 4]) = elu4(acc3);
    }

    // ---- layer3: 64 -> 4; lane l handles node (l>>2), channel (l&3) ----
    {
      int nd = l >> 2, c = l & 3;
      float acc = B3[c];
      #pragma unroll 4
      for (int i = 0; i < 16; ++i) {
        float4 h = *reinterpret_cast<const float4*>(&hrow[(row0 + nd) * HSTRIDE + i * 4]);
        float4 w = *reinterpret_cast<const float4*>(&sW3T[c * 64 + i * 4]);
        acc += h.x * w.x + h.y * w.y + h.z * w.z + h.w * w.w;
      }
      if (nodeBase + nd < n) out[(nodeBase + nd) * 4 + c] = acc;
    }
  }
}

// ---------------- launch ----------------

extern "C" void kernel_launch(void* const* d_in, const int* in_sizes, int n_in,
                              void* d_out, int out_size, void* d_ws, size_t ws_size,
                              hipStream_t stream) {
  const float* x   = (const float*)d_in[0];
  const int*   ei  = (const int*)d_in[1];
  const float* Wl0 = (const float*)d_in[2];
  const float* Wr0 = (const float*)d_in[3];
  const float* bl0 = (const float*)d_in[4];
  const float* Wl1 = (const float*)d_in[5];
  const float* Wr1 = (const float*)d_in[6];
  const float* bl1 = (const float*)d_in[7];
  const float* Wl2 = (const float*)d_in[8];
  const float* Wr2 = (const float*)d_in[9];
  const float* bl2 = (const float*)d_in[10];
  const float* LW0 = (const float*)d_in[11];
  const float* LB0 = (const float*)d_in[12];
  const float* LW1 = (const float*)d_in[13];
  const float* LB1 = (const float*)d_in[14];
  const float* LW2 = (const float*)d_in[15];
  const float* LB2 = (const float*)d_in[16];
  const float* LW3 = (const float*)d_in[17];
  const float* LB3 = (const float*)d_in[18];
  float* out = (float*)d_out;

  const int N_ = in_sizes[0] / 32;   // 100000
  const int E_ = in_sizes[1] / 2;    // 3200000

  const int NB = (N_ + (1 << BSH) - 1) >> BSH;        // 391 buckets
  const int chunk = (E_ + GPART - 1) / GPART;
  const int n2 = NB * GPART;
  const int nb2 = (n2 + 255) / 256;                    // <= 512

  char* wsp = (char*)d_ws;
  int* cnt    = (int*)wsp;  wsp += sizeof(int) * (size_t)n2;
  int* off    = (int*)wsp;  wsp += sizeof(int) * (size_t)n2;
  int* part   = (int*)wsp;  wsp += sizeof(int) * 512;
  int* temp   = (int*)wsp;  wsp += sizeof(int) * (size_t)E_;   // dead after k_fine
  int* csr    = (int*)wsp;  wsp += sizeof(int) * (size_t)E_;
  size_t hBytes = sizeof(float) * (size_t)N_ * DCONV;          // 6.4 MB
  float* H2   = (float*)wsp; wsp += hBytes;
  int* rowptr = (int*)wsp;  wsp += sizeof(int) * (size_t)(N_ + 1);
  float* H0 = (float*)temp;
  float* H1 = (float*)((char*)temp + hBytes);

  // CSR build
  k_hist<<<GPART, 256, 0, stream>>>(ei, E_, NB, chunk, cnt);
  k_block_sums<<<nb2, 256, 0, stream>>>(cnt, n2, part);
  k_scan_part<<<1, 512, 0, stream>>>(part, nb2);
  k_excl_apply<<<nb2, 256, 0, stream>>>(cnt, n2, part, off);
  k_scatter<<<GPART, 256, 0, stream>>>(ei, E_, NB, chunk, off, temp);
  k_fine<<<NB, 256, 0, stream>>>(temp, off, NB, E_, N_, rowptr, csr);

  int nbX = (N_ * 16 + 255) / 256;   // xform grids
  int nbA = (N_ * 4 + 255) / 256;    // agg grids

  // conv0: x -> H2(h1)   [y=H0, r=H1]
  k_xform32<<<nbX, 256, 0, stream>>>(x, Wl0, Wr0, bl0, H0, H1, N_);
  k_agg<<<nbA, 256, 0, stream>>>(H0, H1, rowptr, csr, H2, N_);
  // conv1: H2 -> H1(h2)
  k_xform16<<<nbX, 256, 0, stream>>>(H2, Wl1, Wr1, bl1, H2, H0, N_);
  k_agg<<<nbA, 256, 0, stream>>>(H2, H0, rowptr, csr, H1, N_);
  // conv2: H1 -> H2(h3)
  k_xform16<<<nbX, 256, 0, stream>>>(H1, Wl2, Wr2, bl2, H1, H0, N_);
  k_agg<<<nbA, 256, 0, stream>>>(H1, H0, rowptr, csr, H2, N_);

  // MLP: 16 lanes per group, 4 nodes per group
  int groups = (N_ + 3) / 4;
  int nbM = (groups + 15) / 16;
  k_mlp<<<nbM, 256, 0, stream>>>(H2, LW0, LB0, LW1, LB1, LW2, LB2, LW3, LB3, out, N_);
}

// Round 7
// 261.906 us; speedup vs baseline: 5.2441x; 1.1693x over previous
//
#include <hip/hip_runtime.h>
#include <hip/hip_fp16.h>
#include <math.h>

#define DCONV 16
#define BSH 8            // nodes per bucket = 256
#define GPART 192        // partition blocks
#define MAXNB 512

// ---------------- bucketed CSR build ----------------

__global__ void k_hist(const int* __restrict__ ei, int E, int nb_buckets, int chunk,
                       int* __restrict__ cnt) {
  __shared__ int hist[MAXNB];
  int g = blockIdx.x;
  for (int i = threadIdx.x; i < nb_buckets; i += 256) hist[i] = 0;
  __syncthreads();
  int e0 = g * chunk, e1 = min(e0 + chunk, E);
  for (int e = e0 + threadIdx.x; e < e1; e += 256)
    atomicAdd(&hist[ei[E + e] >> BSH], 1);
  __syncthreads();
  for (int i = threadIdx.x; i < nb_buckets; i += 256)
    cnt[i * GPART + g] = hist[i];
}

__global__ void k_block_sums(const int* __restrict__ in, int n, int* __restrict__ part) {
  int i = blockIdx.x * 256 + threadIdx.x;
  int v = (i < n) ? in[i] : 0;
  #pragma unroll
  for (int off = 32; off > 0; off >>= 1) v += __shfl_down(v, off, 64);
  __shared__ int ws[4];
  if ((threadIdx.x & 63) == 0) ws[threadIdx.x >> 6] = v;
  __syncthreads();
  if (threadIdx.x == 0) part[blockIdx.x] = ws[0] + ws[1] + ws[2] + ws[3];
}

__global__ void k_scan_part(int* __restrict__ part, int nb) {
  __shared__ int s[512];
  int t = threadIdx.x;
  int v = (t < nb) ? part[t] : 0;
  s[t] = v;
  __syncthreads();
  for (int off = 1; off < 512; off <<= 1) {
    int u = (t >= off) ? s[t - off] : 0;
    __syncthreads();
    s[t] += u;
    __syncthreads();
  }
  if (t < nb) part[t] = s[t] - v;  // exclusive prefix
}

__global__ void k_excl_apply(const int* __restrict__ in, int n, const int* __restrict__ part,
                             int* __restrict__ out) {
  __shared__ int s[256];
  int t = threadIdx.x;
  int i = blockIdx.x * 256 + t;
  int v = (i < n) ? in[i] : 0;
  s[t] = v;
  __syncthreads();
  for (int off = 1; off < 256; off <<= 1) {
    int u = (t >= off) ? s[t - off] : 0;
    __syncthreads();
    s[t] += u;
    __syncthreads();
  }
  if (i < n) out[i] = s[t] - v + part[blockIdx.x];
}

__global__ void k_scatter(const int* __restrict__ ei, int E, int nb_buckets, int chunk,
                          const int* __restrict__ off, int* __restrict__ temp) {
  __shared__ int cur[MAXNB];
  int g = blockIdx.x;
  for (int i = threadIdx.x; i < nb_buckets; i += 256) cur[i] = off[i * GPART + g];
  __syncthreads();
  int e0 = g * chunk, e1 = min(e0 + chunk, E);
  for (int e = e0 + threadIdx.x; e < e1; e += 256) {
    int s = ei[e];
    int d = ei[E + e];
    int b = d >> BSH;
    int pos = atomicAdd(&cur[b], 1);
    temp[pos] = (s << BSH) | (d & ((1 << BSH) - 1));
  }
}

__global__ void k_fine(const int* __restrict__ temp, const int* __restrict__ off,
                       int nb_buckets, int E, int n,
                       int* __restrict__ rowptr, int* __restrict__ csr) {
  __shared__ int hist[1 << BSH];
  __shared__ int cur[1 << BSH];
  int b = blockIdx.x, t = threadIdx.x;
  int lo = off[b * GPART];
  int hi = (b == nb_buckets - 1) ? E : off[(b + 1) * GPART];
  hist[t] = 0;
  __syncthreads();
  for (int e = lo + t; e < hi; e += 256)
    atomicAdd(&hist[temp[e] & 255], 1);
  __syncthreads();
  int v = hist[t];
  cur[t] = v;
  __syncthreads();
  for (int offm = 1; offm < 256; offm <<= 1) {
    int u = (t >= offm) ? cur[t - offm] : 0;
    __syncthreads();
    cur[t] += u;
    __syncthreads();
  }
  int excl = cur[t] - v;
  int node = (b << BSH) + t;
  if (node < n) rowptr[node] = lo + excl;
  if (b == nb_buckets - 1 && t == 0) rowptr[n] = hi;
  cur[t] = lo + excl;
  __syncthreads();
  for (int e = lo + t; e < hi; e += 256) {
    int p = temp[e];
    int pos = atomicAdd(&cur[p & 255], 1);
    csr[pos] = p >> BSH;
  }
}

// ---------------- pre-transform: y = fp16(h @ Wl) ----------------
// (mean and matmul commute; the root/bias term h@Wr+b is fused into k_agg)

__global__ void k_xform32h(const float* __restrict__ xin,
                           const float* __restrict__ Wl,
                           __half* __restrict__ y, int n) {
  __shared__ float sWl[32 * 16];
  int t = threadIdx.x;
  for (int i = t; i < 32 * 16; i += 256) sWl[i] = Wl[i];
  __syncthreads();
  int l = t & 15;
  int base = (t & 63) & ~15;
  int node = (blockIdx.x * 256 + t) >> 4;
  if (node >= n) return;
  float x0 = xin[node * 32 + l];
  float x1 = xin[node * 32 + 16 + l];
  float ay = 0.f;
  #pragma unroll
  for (int i = 0; i < 16; ++i) {
    float v0 = __shfl(x0, base + i, 64);
    float v1 = __shfl(x1, base + i, 64);
    ay += v0 * sWl[i * 16 + l] + v1 * sWl[(16 + i) * 16 + l];
  }
  y[node * 16 + l] = __float2half_rn(ay);
}

__global__ void k_xform16h(const float* __restrict__ hin,
                           const float* __restrict__ Wl,
                           __half* __restrict__ y, int n) {
  __shared__ float sWl[16 * 16];
  int t = threadIdx.x;
  for (int i = t; i < 16 * 16; i += 256) sWl[i] = Wl[i];
  __syncthreads();
  int l = t & 15;
  int base = (t & 63) & ~15;
  int node = (blockIdx.x * 256 + t) >> 4;
  if (node >= n) return;
  float x0 = hin[node * 16 + l];
  float ay = 0.f;
  #pragma unroll
  for (int i = 0; i < 16; ++i) {
    float v0 = __shfl(x0, base + i, 64);
    ay += v0 * sWl[i * 16 + l];
  }
  y[node * 16 + l] = __float2half_rn(ay);
}

// ---------------- aggregate: out = elu(mean_gather(y16) + h@Wr + b) ----------------
// 4 lanes/node, each lane owns 4 channels (8B fp16 per edge). y16 = 3.2 MB ->
// fully L2-resident per XCD; the root term is computed in-kernel (VALU is idle).

template <int DI>
__global__ void k_agg(const __half* __restrict__ y, const float* __restrict__ hin,
                      const float* __restrict__ Wr, const float* __restrict__ bias,
                      const int* __restrict__ rowptr, const int* __restrict__ csr,
                      float* __restrict__ outp, int n) {
  __shared__ __align__(16) float sWr[DI * 16];
  __shared__ float sb[16];
  {
    int tt = threadIdx.x;
    for (int i = tt; i < DI * 16; i += 256) sWr[i] = Wr[i];
    if (tt < 16) sb[tt] = bias[tt];
  }
  __syncthreads();

  int t = blockIdx.x * 256 + threadIdx.x;
  int l = t & 3;
  int node = t >> 2;
  if (node >= n) return;
  int r0 = rowptr[node], r1 = rowptr[node + 1];

  const uint2* __restrict__ yv = reinterpret_cast<const uint2*>(y);

  float a0 = 0.f, a1 = 0.f, a2 = 0.f, a3 = 0.f;
  float b0 = 0.f, b1 = 0.f, b2 = 0.f, b3 = 0.f;
  float c0 = 0.f, c1 = 0.f, c2 = 0.f, c3 = 0.f;
  float d0 = 0.f, d1 = 0.f, d2 = 0.f, d3 = 0.f;
  int k = r0;
  for (; k + 3 < r1; k += 4) {
    int ia = csr[k], ib = csr[k + 1], ic = csr[k + 2], id = csr[k + 3];
    uint2 ra = yv[ia * 4 + l];
    uint2 rb = yv[ib * 4 + l];
    uint2 rc = yv[ic * 4 + l];
    uint2 rd = yv[id * 4 + l];
    float2 fa0 = __half22float2(*reinterpret_cast<const __half2*>(&ra.x));
    float2 fa1 = __half22float2(*reinterpret_cast<const __half2*>(&ra.y));
    float2 fb0 = __half22float2(*reinterpret_cast<const __half2*>(&rb.x));
    float2 fb1 = __half22float2(*reinterpret_cast<const __half2*>(&rb.y));
    float2 fc0 = __half22float2(*reinterpret_cast<const __half2*>(&rc.x));
    float2 fc1 = __half22float2(*reinterpret_cast<const __half2*>(&rc.y));
    float2 fd0 = __half22float2(*reinterpret_cast<const __half2*>(&rd.x));
    float2 fd1 = __half22float2(*reinterpret_cast<const __half2*>(&rd.y));
    a0 += fa0.x; a1 += fa0.y; a2 += fa1.x; a3 += fa1.y;
    b0 += fb0.x; b1 += fb0.y; b2 += fb1.x; b3 += fb1.y;
    c0 += fc0.x; c1 += fc0.y; c2 += fc1.x; c3 += fc1.y;
    d0 += fd0.x; d1 += fd0.y; d2 += fd1.x; d3 += fd1.y;
  }
  for (; k < r1; ++k) {
    int ia = csr[k];
    uint2 ra = yv[ia * 4 + l];
    float2 fa0 = __half22float2(*reinterpret_cast<const __half2*>(&ra.x));
    float2 fa1 = __half22float2(*reinterpret_cast<const __half2*>(&ra.y));
    a0 += fa0.x; a1 += fa0.y; a2 += fa1.x; a3 += fa1.y;
  }
  float s0 = a0 + b0 + c0 + d0;
  float s1 = a1 + b1 + c1 + d1;
  float s2 = a2 + b2 + c2 + d2;
  float s3 = a3 + b3 + c3 + d3;
  float inv = 1.f / fmaxf((float)(r1 - r0), 1.f);

  // root term: channels cbase..cbase+3 of hin[node] @ Wr + b
  int cbase = l * 4;
  float4 rr = *reinterpret_cast<const float4*>(&sb[cbase]);
  #pragma unroll
  for (int i = 0; i < DI; ++i) {
    float h = hin[node * DI + i];
    float4 w = *reinterpret_cast<const float4*>(&sWr[i * 16 + cbase]);
    rr.x += h * w.x; rr.y += h * w.y; rr.z += h * w.z; rr.w += h * w.w;
  }

  float ax = s0 * inv + rr.x;
  float ay = s1 * inv + rr.y;
  float az = s2 * inv + rr.z;
  float aw = s3 * inv + rr.w;
  float4 o;
  o.x = ax > 0.f ? ax : (__expf(ax) - 1.f);
  o.y = ay > 0.f ? ay : (__expf(ay) - 1.f);
  o.z = az > 0.f ? az : (__expf(az) - 1.f);
  o.w = aw > 0.f ? aw : (__expf(aw) - 1.f);
  *reinterpret_cast<float4*>(&outp[node * 16 + cbase]) = o;
}

// ---------------- fused 4-layer MLP (16 lanes/group, 4 nodes/group) ----------------

#define HSTRIDE 68

__device__ __forceinline__ float4 elu4(float4 a) {
  float4 r;
  r.x = a.x > 0.f ? a.x : (__expf(a.x) - 1.f);
  r.y = a.y > 0.f ? a.y : (__expf(a.y) - 1.f);
  r.z = a.z > 0.f ? a.z : (__expf(a.z) - 1.f);
  r.w = a.w > 0.f ? a.w : (__expf(a.w) - 1.f);
  return r;
}

__device__ __forceinline__ void fma16(float4& a, const float4 h,
                                      const float4 w0, const float4 w1,
                                      const float4 w2, const float4 w3) {
  a.x += h.x * w0.x + h.y * w1.x + h.z * w2.x + h.w * w3.x;
  a.y += h.x * w0.y + h.y * w1.y + h.z * w2.y + h.w * w3.y;
  a.z += h.x * w0.z + h.y * w1.z + h.z * w2.z + h.w * w3.z;
  a.w += h.x * w0.w + h.y * w1.w + h.z * w2.w + h.w * w3.w;
}

__global__ void __launch_bounds__(256) k_mlp(
    const float* __restrict__ xin,
    const float* __restrict__ W0, const float* __restrict__ B0,
    const float* __restrict__ W1, const float* __restrict__ B1,
    const float* __restrict__ W2, const float* __restrict__ B2,
    const float* __restrict__ W3, const float* __restrict__ B3,
    float* __restrict__ out, int n) {
  __shared__ __align__(16) float hrow[64 * HSTRIDE];  // 16 groups * 4 rows
  __shared__ __align__(16) float sW3T[4 * 64];        // W3 transposed: [c][i]
  int t = threadIdx.x;
  int l = t & 15;
  int gb = t >> 4;
  int group = blockIdx.x * 16 + gb;
  int nodeBase = group * 4;
  bool active = nodeBase < n;
  int row0 = gb * 4;

  sW3T[(t & 3) * 64 + (t >> 2)] = W3[t];

  if (active) {
    int nd = l >> 2;
    float4 v = make_float4(0.f, 0.f, 0.f, 0.f);
    if (nodeBase + nd < n)
      v = *reinterpret_cast<const float4*>(&xin[nodeBase * 16 + l * 4]);
    *reinterpret_cast<float4*>(&hrow[(row0 + nd) * HSTRIDE + (l & 3) * 4]) = v;
  }
  __syncthreads();

  if (active) {
    float4 acc0, acc1, acc2, acc3;

    // ---- layer0: 16 -> 64 ----
    acc0 = *reinterpret_cast<const float4*>(&B0[4 * l]);
    acc1 = acc0; acc2 = acc0; acc3 = acc0;
    #pragma unroll
    for (int j = 0; j < 4; ++j) {
      float4 h0 = *reinterpret_cast<const float4*>(&hrow[(row0 + 0) * HSTRIDE + j * 4]);
      float4 h1 = *reinterpret_cast<const float4*>(&hrow[(row0 + 1) * HSTRIDE + j * 4]);
      float4 h2 = *reinterpret_cast<const float4*>(&hrow[(row0 + 2) * HSTRIDE + j * 4]);
      float4 h3 = *reinterpret_cast<const float4*>(&hrow[(row0 + 3) * HSTRIDE + j * 4]);
      float4 w0 = *reinterpret_cast<const float4*>(&W0[(4 * j + 0) * 64 + 4 * l]);
      float4 w1 = *reinterpret_cast<const float4*>(&W0[(4 * j + 1) * 64 + 4 * l]);
      float4 w2 = *reinterpret_cast<const float4*>(&W0[(4 * j + 2) * 64 + 4 * l]);
      float4 w3 = *reinterpret_cast<const float4*>(&W0[(4 * j + 3) * 64 + 4 * l]);
      fma16(acc0, h0, w0, w1, w2, w3);
      fma16(acc1, h1, w0, w1, w2, w3);
      fma16(acc2, h2, w0, w1, w2, w3);
      fma16(acc3, h3, w0, w1, w2, w3);
    }
    *reinterpret_cast<float4*>(&hrow[(row0 + 0) * HSTRIDE + l * 4]) = elu4(acc0);
    *reinterpret_cast<float4*>(&hrow[(row0 + 1) * HSTRIDE + l * 4]) = elu4(acc1);
    *reinterpret_cast<float4*>(&hrow[(row0 + 2) * HSTRIDE + l * 4]) = elu4(acc2);
    *reinterpret_cast<float4*>(&hrow[(row0 + 3) * HSTRIDE + l * 4]) = elu4(acc3);

    // ---- layers 1 & 2: 64 -> 64 ----
    const float* Ws[2] = {W1, W2};
    const float* Bs[2] = {B1, B2};
    #pragma unroll
    for (int layer = 0; layer < 2; ++layer) {
      const float* __restrict__ W = Ws[layer];
      acc0 = *reinterpret_cast<const float4*>(&Bs[layer][4 * l]);
      acc1 = acc0; acc2 = acc0; acc3 = acc0;
      #pragma unroll 4
      for (int j = 0; j < 16; ++j) {
        float4 h0 = *reinterpret_cast<const float4*>(&hrow[(row0 + 0) * HSTRIDE + j * 4]);
        float4 h1 = *reinterpret_cast<const float4*>(&hrow[(row0 + 1) * HSTRIDE + j * 4]);
        float4 h2 = *reinterpret_cast<const float4*>(&hrow[(row0 + 2) * HSTRIDE + j * 4]);
        float4 h3 = *reinterpret_cast<const float4*>(&hrow[(row0 + 3) * HSTRIDE + j * 4]);
        float4 w0 = *reinterpret_cast<const float4*>(&W[(4 * j + 0) * 64 + 4 * l]);
        float4 w1 = *reinterpret_cast<const float4*>(&W[(4 * j + 1) * 64 + 4 * l]);
        float4 w2 = *reinterpret_cast<const float4*>(&W[(4 * j + 2) * 64 + 4 * l]);
        float4 w3 = *reinterpret_cast<const float4*>(&W[(4 * j + 3) * 64 + 4 * l]);
        fma16(acc0, h0, w0, w1, w2, w3);
        fma16(acc1, h1, w0, w1, w2, w3);
        fma16(acc2, h2, w0, w1, w2, w3);
        fma16(acc3, h3, w0, w1, w2, w3);
      }
      *reinterpret_cast<float4*>(&hrow[(row0 + 0) * HSTRIDE + l * 4]) = elu4(acc0);
      *reinterpret_cast<float4*>(&hrow[(row0 + 1) * HSTRIDE + l * 4]) = elu4(acc1);
      *reinterpret_cast<float4*>(&hrow[(row0 + 2) * HSTRIDE + l * 4]) = elu4(acc2);
      *reinterpret_cast<float4*>(&hrow[(row0 + 3) * HSTRIDE + l * 4]) = elu4(acc3);
    }

    // ---- layer3: 64 -> 4; lane l handles node (l>>2), channel (l&3) ----
    {
      int nd = l >> 2, c = l & 3;
      float acc = B3[c];
      #pragma unroll 4
      for (int i = 0; i < 16; ++i) {
        float4 h = *reinterpret_cast<const float4*>(&hrow[(row0 + nd) * HSTRIDE + i * 4]);
        float4 w = *reinterpret_cast<const float4*>(&sW3T[c * 64 + i * 4]);
        acc += h.x * w.x + h.y * w.y + h.z * w.z + h.w * w.w;
      }
      if (nodeBase + nd < n) out[(nodeBase + nd) * 4 + c] = acc;
    }
  }
}

// ---------------- launch ----------------

extern "C" void kernel_launch(void* const* d_in, const int* in_sizes, int n_in,
                              void* d_out, int out_size, void* d_ws, size_t ws_size,
                              hipStream_t stream) {
  const float* x   = (const float*)d_in[0];
  const int*   ei  = (const int*)d_in[1];
  const float* Wl0 = (const float*)d_in[2];
  const float* Wr0 = (const float*)d_in[3];
  const float* bl0 = (const float*)d_in[4];
  const float* Wl1 = (const float*)d_in[5];
  const float* Wr1 = (const float*)d_in[6];
  const float* bl1 = (const float*)d_in[7];
  const float* Wl2 = (const float*)d_in[8];
  const float* Wr2 = (const float*)d_in[9];
  const float* bl2 = (const float*)d_in[10];
  const float* LW0 = (const float*)d_in[11];
  const float* LB0 = (const float*)d_in[12];
  const float* LW1 = (const float*)d_in[13];
  const float* LB1 = (const float*)d_in[14];
  const float* LW2 = (const float*)d_in[15];
  const float* LB2 = (const float*)d_in[16];
  const float* LW3 = (const float*)d_in[17];
  const float* LB3 = (const float*)d_in[18];
  float* out = (float*)d_out;

  const int N_ = in_sizes[0] / 32;   // 100000
  const int E_ = in_sizes[1] / 2;    // 3200000

  const int NB = (N_ + (1 << BSH) - 1) >> BSH;        // 391 buckets
  const int chunk = (E_ + GPART - 1) / GPART;
  const int n2 = NB * GPART;
  const int nb2 = (n2 + 255) / 256;                    // <= 512

  char* wsp = (char*)d_ws;
  int* cnt    = (int*)wsp;  wsp += sizeof(int) * (size_t)n2;
  int* off    = (int*)wsp;  wsp += sizeof(int) * (size_t)n2;
  int* part   = (int*)wsp;  wsp += sizeof(int) * 512;
  int* temp   = (int*)wsp;  wsp += sizeof(int) * (size_t)E_;   // 12.8 MB, dead after k_fine
  int* csr    = (int*)wsp;  wsp += sizeof(int) * (size_t)E_;
  size_t hBytes = sizeof(float) * (size_t)N_ * DCONV;          // 6.4 MB
  float* Ha   = (float*)wsp; wsp += hBytes;
  int* rowptr = (int*)wsp;  wsp += sizeof(int) * (size_t)(N_ + 1);
  // reuse temp: y16 (3.2 MB) + Hb (6.4 MB) <= 12.8 MB
  __half* y16 = (__half*)temp;
  float*  Hb  = (float*)((char*)temp + sizeof(__half) * (size_t)N_ * DCONV);

  // CSR build
  k_hist<<<GPART, 256, 0, stream>>>(ei, E_, NB, chunk, cnt);
  k_block_sums<<<nb2, 256, 0, stream>>>(cnt, n2, part);
  k_scan_part<<<1, 512, 0, stream>>>(part, nb2);
  k_excl_apply<<<nb2, 256, 0, stream>>>(cnt, n2, part, off);
  k_scatter<<<GPART, 256, 0, stream>>>(ei, E_, NB, chunk, off, temp);
  k_fine<<<NB, 256, 0, stream>>>(temp, off, NB, E_, N_, rowptr, csr);

  int nbX = (N_ * 16 + 255) / 256;   // xform grids
  int nbA = (N_ * 4 + 255) / 256;    // agg grids

  // conv0: x -> Ha
  k_xform32h<<<nbX, 256, 0, stream>>>(x, Wl0, y16, N_);
  k_agg<32><<<nbA, 256, 0, stream>>>(y16, x, Wr0, bl0, rowptr, csr, Ha, N_);
  // conv1: Ha -> Hb
  k_xform16h<<<nbX, 256, 0, stream>>>(Ha, Wl1, y16, N_);
  k_agg<16><<<nbA, 256, 0, stream>>>(y16, Ha, Wr1, bl1, rowptr, csr, Hb, N_);
  // conv2: Hb -> Ha
  k_xform16h<<<nbX, 256, 0, stream>>>(Hb, Wl2, y16, N_);
  k_agg<16><<<nbA, 256, 0, stream>>>(y16, Hb, Wr2, bl2, rowptr, csr, Ha, N_);

  // MLP: 16 lanes per group, 4 nodes per group
  int groups = (N_ + 3) / 4;
  int nbM = (groups + 15) / 16;
  k_mlp<<<nbM, 256, 0, stream>>>(Ha, LW0, LB0, LW1, LB1, LW2, LB2, LW3, LB3, out, N_);
}